// Round 8
// baseline (460.856 us; speedup 1.0000x reference)
//
#include <hip/hip_runtime.h>

typedef unsigned short u16;
typedef unsigned int   u32;
typedef short bf16x8 __attribute__((ext_vector_type(8)));
typedef float f32x4  __attribute__((ext_vector_type(4)));
typedef float f32x2  __attribute__((ext_vector_type(2)));

#define BG    128      // graphs
#define NN    128      // nodes per graph
#define MS    16       // samples
#define KP    8        // pearl_k
#define HM    16       // mlp hidden
#define DP    64       // pe dims
#define NSUM  16384    // BG*NN
#define NE    262144   // edges
#define SITES 2048     // NN*MS

// R3: inputs f32, output f32. Intermediates bf16.
// R6/R7: m-sliced gathers proven L2-resident (FETCH 248->57MB); R7 VALU-bound.
// R8: fuse agg+MLP per m-pair (z1/z2 eliminated); out accumulated via
//     atomicAdd over 8 m-pair partials; poly at 512 threads; 6 launches.

__device__ __forceinline__ float blo(u32 u){ union{u32 i; float f;} v; v.i=u<<16; return v.f; }
__device__ __forceinline__ float bhi(u32 u){ union{u32 i; float f;} v; v.i=u&0xffff0000u; return v.f; }
__device__ __forceinline__ u16  f2b(float f){ union{float f; u32 i;} v; v.f=f; u32 x=v.i; x += 0x7fffu + ((x>>16)&1u); return (u16)(x>>16); }
__device__ __forceinline__ u32  pk2(float a, float b){ return (u32)f2b(a) | ((u32)f2b(b)<<16); }

__device__ __forceinline__ f32x2 up2(u32 u){ f32x2 v; v.x=blo(u); v.y=bhi(u); return v; }
__device__ __forceinline__ void accp4(f32x2* A, uint2 x){ A[0]+=up2(x.x); A[1]+=up2(x.y); }
__device__ __forceinline__ void accp8(f32x2* A, uint4 x){
  A[0]+=up2(x.x); A[1]+=up2(x.y); A[2]+=up2(x.z); A[3]+=up2(x.w);
}

#define MFMA16(a,b,c) __builtin_amdgcn_mfma_f32_16x16x32_bf16(a,b,c,0,0,0)

// B-operand frag: W row-major [nrows][64] f32 global; n=nb+col, k=k0+quad*8+j.
__device__ __forceinline__ bf16x8 bfragW(const float* __restrict__ W, int nrows,
                                         int k0, int nb, int col, int quad){
  bf16x8 f;
  #pragma unroll
  for(int j=0;j<8;++j){
    int k = k0 + quad*8 + j;
    float v = (k < nrows) ? W[k*DP + nb + col] : 0.f;
    f[j] = (short)f2b(v);
  }
  return f;
}
// A-operand frag from f32 LDS tile (stride 68 f32).
__device__ __forceinline__ bf16x8 afragT(const float* tp){
  float4 v0 = *(const float4*)tp;
  float4 v1 = *(const float4*)(tp+4);
  bf16x8 a;
  a[0]=(short)f2b(v0.x); a[1]=(short)f2b(v0.y); a[2]=(short)f2b(v0.z); a[3]=(short)f2b(v0.w);
  a[4]=(short)f2b(v1.x); a[5]=(short)f2b(v1.y); a[6]=(short)f2b(v1.z); a[7]=(short)f2b(v1.w);
  return a;
}

// ---------------------------------------------------------------------------
// K1: per-graph polynomial filter + MLP over k + BN + ReLU. 512 threads:
// thread owns (n, 4 m's). Also zeroes cnt[] for the CSR histogram.
// h1T[m][node][c] bf16.
// ---------------------------------------------------------------------------
__global__ __launch_bounds__(512) void k_poly(
    const float* __restrict__ lap, const float* __restrict__ W0, const float* __restrict__ mlpW,
    const float* __restrict__ bng, const float* __restrict__ bnb, u16* __restrict__ h1T,
    int* __restrict__ cnt)
{
  __shared__ float Wbuf[2][SITES];   // 16 KB
  __shared__ float mlpWS[KP*HM];
  __shared__ float red[8][32];
  __shared__ float stat[32];
  __shared__ float ssc[HM], ssh[HM];

  const int b = blockIdx.x, t = threadIdx.x;
  {
    int gi = b*512 + t;
    if (gi < NSUM) cnt[gi] = 0;
  }
  for (int i=t; i<SITES; i+=512) Wbuf[0][i] = W0[(size_t)b*SITES+i];
  if (t < KP*HM) mlpWS[t] = mlpW[t];
  __syncthreads();

  const int n = t>>2, m0 = (t&3)*4;      // thread owns sites (n, m0..m0+3)
  float h[4][16];
  {
    float mw[16];
    #pragma unroll
    for(int c=0;c<16;++c) mw[c]=mlpWS[c];
    #pragma unroll
    for(int si=0;si<4;++si){
      float f0 = Wbuf[0][n*MS+m0+si];
      #pragma unroll
      for(int c=0;c<16;++c) h[si][c] = f0*mw[c];
    }
  }
  int cur=0;
  const float* lgf = lap + (size_t)b*NN*NN + (size_t)n*NN;
  for(int k=1;k<KP;++k){
    float acc[4] = {0.f,0.f,0.f,0.f};
    const float* wb = &Wbuf[cur][m0];
    for(int j=0;j<NN;j+=2){
      float2 lv = *(const float2*)&lgf[j];
      float a0 = lv.x, a1 = lv.y;
      float4 w0 = *(const float4*)&wb[j*MS];
      float4 w1 = *(const float4*)&wb[(j+1)*MS];
      acc[0]+=a0*w0.x; acc[1]+=a0*w0.y; acc[2]+=a0*w0.z; acc[3]+=a0*w0.w;
      acc[0]+=a1*w1.x; acc[1]+=a1*w1.y; acc[2]+=a1*w1.z; acc[3]+=a1*w1.w;
    }
    __syncthreads();
    {
      float4 av; av.x=acc[0]; av.y=acc[1]; av.z=acc[2]; av.w=acc[3];
      *(float4*)&Wbuf[cur^1][n*MS+m0] = av;
      float mw[16];
      #pragma unroll
      for(int c=0;c<16;++c) mw[c]=mlpWS[k*16+c];
      #pragma unroll
      for(int si=0;si<4;++si){
        #pragma unroll
        for(int c=0;c<16;++c) h[si][c] += acc[si]*mw[c];
      }
    }
    __syncthreads();
    cur ^= 1;
  }
  // BN stats over 2048 sites per channel
  float sum[16], sq[16];
  #pragma unroll
  for(int c=0;c<16;++c){ sum[c]=0.f; sq[c]=0.f; }
  #pragma unroll
  for(int si=0;si<4;++si){
    #pragma unroll
    for(int c=0;c<16;++c){ float v=h[si][c]; sum[c]+=v; sq[c]+=v*v; }
  }
  #pragma unroll
  for(int d=1;d<64;d<<=1){
    #pragma unroll
    for(int c=0;c<16;++c){ sum[c]+=__shfl_xor(sum[c],d,64); sq[c]+=__shfl_xor(sq[c],d,64); }
  }
  const int lane=t&63, wid=t>>6;
  if(lane==0){
    #pragma unroll
    for(int c=0;c<16;++c){ red[wid][c]=sum[c]; red[wid][16+c]=sq[c]; }
  }
  __syncthreads();
  if(t<32){
    float s=0.f;
    #pragma unroll
    for(int ww=0;ww<8;++ww) s += red[ww][t];
    stat[t]=s;
  }
  __syncthreads();
  if(t<16){
    float mu  = stat[t]*(1.f/SITES);
    float var = stat[16+t]*(1.f/SITES) - mu*mu;
    float sc  = bng[t] * rsqrtf(var + 1e-5f);
    ssc[t]=sc; ssh[t]=bnb[t] - mu*sc;
  }
  __syncthreads();
  {
    const int node = b*NN + n;
    float sc[16], sh[16];
    #pragma unroll
    for(int c=0;c<16;++c){ sc[c]=ssc[c]; sh[c]=ssh[c]; }
    #pragma unroll
    for(int si=0;si<4;++si){
      float r[16];
      #pragma unroll
      for(int c=0;c<16;++c) r[c]=fmaxf(h[si][c]*sc[c]+sh[c], 0.f);
      uint4 A, Bv;
      A.x =pk2(r[0],r[1]);   A.y =pk2(r[2],r[3]);   A.z =pk2(r[4],r[5]);   A.w =pk2(r[6],r[7]);
      Bv.x=pk2(r[8],r[9]);   Bv.y=pk2(r[10],r[11]); Bv.z=pk2(r[12],r[13]); Bv.w=pk2(r[14],r[15]);
      u16* o = h1T + ((size_t)(m0+si)*NSUM + node)*HM;
      *(uint4*)o     = A;
      *(uint4*)(o+8) = Bv;
    }
  }
}

// --------------------------- CSR build (by dst) ----------------------------
__global__ void k_hist(const int* __restrict__ dst, int* __restrict__ cnt){
  int e = blockIdx.x*256 + threadIdx.x;
  atomicAdd(&cnt[dst[e]], 1);
}

__global__ void k_scan(const int* __restrict__ cnt, int* __restrict__ off, int* __restrict__ wpos){
  __shared__ int ps[256];
  const int t = threadIdx.x, PER = NSUM/256;
  int s=0;
  for(int i=0;i<PER;++i) s += cnt[t*PER+i];
  ps[t]=s; __syncthreads();
  for(int d=1; d<256; d<<=1){
    int v = (t>=d) ? ps[t-d] : 0;
    __syncthreads();
    ps[t] += v;
    __syncthreads();
  }
  int run = (t==0) ? 0 : ps[t-1];
  for(int i=0;i<PER;++i){
    int idx=t*PER+i;
    off[idx]=run; wpos[idx]=run;
    run += cnt[idx];
  }
  if(t==255) off[NSUM]=run;
}

// scatter also zeroes d_out (needed before k_gin2f's atomic accumulation)
__global__ void k_scatter(const int* __restrict__ srcI, const int* __restrict__ dstI,
                          int* __restrict__ wpos, int* __restrict__ srcs,
                          float4* __restrict__ outz){
  int e = blockIdx.x*256 + threadIdx.x;
  float4 z; z.x=0.f; z.y=0.f; z.z=0.f; z.w=0.f;
  outz[e] = z;                          // 262144 float4 == out exactly
  int p = atomicAdd(&wpos[dstI[e]], 1);
  srcs[p] = srcI[e];
}

// ---------------------------------------------------------------------------
// K5: fused GIN-1 (aggregate + MLP). Block = (m-pair, 64 nodes); wave = 16
// nodes. Gather: 16 slots x 8B chunks over h1T slices m, m+8 (XCD-local);
// shfl-combine; rows (node,m) -> LDS A-tile (k padded to 32) -> MFMA ->
// h2T[m][node][64] bf16.
// ---------------------------------------------------------------------------
__global__ __launch_bounds__(256) void k_gin1f(
  const u16* __restrict__ h1T, const float* __restrict__ W1a, const float* __restrict__ b1a,
  const float* __restrict__ W1b, const float* __restrict__ b1b, const float* __restrict__ eps1p,
  const int* __restrict__ off, const int* __restrict__ srcs, u16* __restrict__ h2T)
{
  __shared__ u16   zS[4][32*40];        // 10 KB  (rows stride 40 u16 = 80 B)
  __shared__ float tS[4][16*68 + 4];    // 17.5 KB
  const int t=threadIdx.x, l=t&63, w=t>>6;
  const int col=l&15, quad=l>>4;
  const int mp = blockIdx.x & 7, g = blockIdx.x >> 3;
  const u16* __restrict__ base0 = h1T + (size_t)mp*NSUM*HM;
  const u16* __restrict__ base1 = h1T + (size_t)(mp+8)*NSUM*HM;
  u16* __restrict__ ob0 = h2T + (size_t)mp*NSUM*DP;
  u16* __restrict__ ob1 = h2T + (size_t)(mp+8)*NSUM*DP;
  const float epe = 1.f + eps1p[0];

  // zero the k-pad region (u16 16..31 of each of 32 rows), once
  for(int i=l; i<32*8; i+=64){
    int row = i>>3, c = i&7;
    *(u32*)&zS[w][row*40 + 16 + c*2] = 0;
  }

  bf16x8 fa[4], fb[4][2];
  float bav[4], bbv[4];
  #pragma unroll
  for(int nt=0;nt<4;++nt){
    fa[nt]    = bfragW(W1a, HM, 0,  nt*16, col, quad);   // k>=16 zeroed
    fb[nt][0] = bfragW(W1b, DP, 0,  nt*16, col, quad);
    fb[nt][1] = bfragW(W1b, DP, 32, nt*16, col, quad);
    bav[nt] = b1a[nt*16+col];
    bbv[nt] = b1b[nt*16+col];
  }

  const int slot = l>>2, q = l&3;
  const int nbase = g*64 + w*16;
  for(int nl=0; nl<16; ++nl){
    const int node = nbase + nl;
    f32x2 A0[2], A1[2];
    {
      f32x2 sv; sv.x = (slot==0)?epe:0.f; sv.y = sv.x;
      uint2 x0 = *(const uint2*)&base0[(size_t)node*HM + q*4];
      uint2 x1 = *(const uint2*)&base1[(size_t)node*HM + q*4];
      A0[0]=sv*up2(x0.x); A0[1]=sv*up2(x0.y);
      A1[0]=sv*up2(x1.x); A1[1]=sv*up2(x1.y);
    }
    const int e1 = off[node+1];
    int e = off[node] + slot;
    for(; e+16<e1; e+=32){
      int s0=srcs[e], s1=srcs[e+16];
      uint2 xa0=*(const uint2*)&base0[(size_t)s0*HM + q*4];
      uint2 xb0=*(const uint2*)&base1[(size_t)s0*HM + q*4];
      uint2 xa1=*(const uint2*)&base0[(size_t)s1*HM + q*4];
      uint2 xb1=*(const uint2*)&base1[(size_t)s1*HM + q*4];
      accp4(A0,xa0); accp4(A1,xb0); accp4(A0,xa1); accp4(A1,xb1);
    }
    if(e<e1){
      int s0=srcs[e];
      uint2 xa0=*(const uint2*)&base0[(size_t)s0*HM + q*4];
      uint2 xb0=*(const uint2*)&base1[(size_t)s0*HM + q*4];
      accp4(A0,xa0); accp4(A1,xb0);
    }
    #pragma unroll
    for(int d2=4; d2<64; d2<<=1){
      A0[0].x+=__shfl_xor(A0[0].x,d2,64); A0[0].y+=__shfl_xor(A0[0].y,d2,64);
      A0[1].x+=__shfl_xor(A0[1].x,d2,64); A0[1].y+=__shfl_xor(A0[1].y,d2,64);
      A1[0].x+=__shfl_xor(A1[0].x,d2,64); A1[0].y+=__shfl_xor(A1[0].y,d2,64);
      A1[1].x+=__shfl_xor(A1[1].x,d2,64); A1[1].y+=__shfl_xor(A1[1].y,d2,64);
    }
    if(l<4){
      uint2 o0; o0.x=pk2(A0[0].x,A0[0].y); o0.y=pk2(A0[1].x,A0[1].y);
      uint2 o1; o1.x=pk2(A1[0].x,A1[0].y); o1.y=pk2(A1[1].x,A1[1].y);
      *(uint2*)&zS[w][(nl*2+0)*40 + l*4] = o0;
      *(uint2*)&zS[w][(nl*2+1)*40 + l*4] = o1;
    }
  }

  // MFMA phase: 2 A-tiles of 16 rows (row = node_local*2 + mi)
  for(int tt=0; tt<2; ++tt){
    bf16x8 a0 = *(const bf16x8*)&zS[w][(tt*16+col)*40 + quad*8];
    #pragma unroll
    for(int nt=0;nt<4;++nt){
      f32x4 c; c[0]=bav[nt]; c[1]=bav[nt]; c[2]=bav[nt]; c[3]=bav[nt];
      c = MFMA16(a0, fa[nt], c);
      #pragma unroll
      for(int r=0;r<4;++r)
        tS[w][(quad*4+r)*68 + nt*16 + col] = fmaxf(c[r], 0.f);
    }
    bf16x8 ta0 = afragT(&tS[w][col*68 + quad*8]);
    bf16x8 ta1 = afragT(&tS[w][col*68 + 32 + quad*8]);
    #pragma unroll
    for(int nt=0;nt<4;++nt){
      f32x4 c; c[0]=bbv[nt]; c[1]=bbv[nt]; c[2]=bbv[nt]; c[3]=bbv[nt];
      c = MFMA16(ta0, fb[nt][0], c);
      c = MFMA16(ta1, fb[nt][1], c);
      #pragma unroll
      for(int r=0;r<4;++r){
        const int node = nbase + tt*8 + quad*2 + (r>>1);
        u16* bp = (r&1) ? ob1 : ob0;
        bp[(size_t)node*DP + nt*16 + col] = f2b(fmaxf(c[r], 0.f));
      }
    }
  }
}

// ---------------------------------------------------------------------------
// K6: fused GIN-2 (aggregate + MLP + ReLU + m-sum). Gather: 8 slots x 16B
// chunks over h2T slices m, m+8; MFMA MLP2; partial sum over the m-pair;
// atomicAdd into out (zeroed by k_scatter).
// ---------------------------------------------------------------------------
__global__ __launch_bounds__(256) void k_gin2f(
  const u16* __restrict__ h2T, const float* __restrict__ W2a, const float* __restrict__ b2a,
  const float* __restrict__ W2b, const float* __restrict__ b2b, const float* __restrict__ eps2p,
  const int* __restrict__ off, const int* __restrict__ srcs, float* __restrict__ out)
{
  __shared__ u16   zS[4][32*72];        // 18 KB  (rows stride 72 u16 = 144 B)
  __shared__ float tS[4][16*68 + 4];    // 17.5 KB
  const int t=threadIdx.x, l=t&63, w=t>>6;
  const int col=l&15, quad=l>>4;
  const int mp = blockIdx.x & 7, g = blockIdx.x >> 3;
  const u16* __restrict__ base0 = h2T + (size_t)mp*NSUM*DP;
  const u16* __restrict__ base1 = h2T + (size_t)(mp+8)*NSUM*DP;
  const float epe = 1.f + eps2p[0];

  bf16x8 fa[4][2], fb[4][2];
  float bav[4], bbv[4];
  #pragma unroll
  for(int nt=0;nt<4;++nt){
    fa[nt][0] = bfragW(W2a, DP, 0,  nt*16, col, quad);
    fa[nt][1] = bfragW(W2a, DP, 32, nt*16, col, quad);
    fb[nt][0] = bfragW(W2b, DP, 0,  nt*16, col, quad);
    fb[nt][1] = bfragW(W2b, DP, 32, nt*16, col, quad);
    bav[nt] = b2a[nt*16+col];
    bbv[nt] = b2b[nt*16+col];
  }

  const int slot = l>>3, q = l&7;
  const int nbase = g*64 + w*16;
  for(int nl=0; nl<16; ++nl){
    const int node = nbase + nl;
    f32x2 A0[4], A1[4];
    {
      f32x2 sv; sv.x = (slot==0)?epe:0.f; sv.y = sv.x;
      uint4 x0 = *(const uint4*)&base0[(size_t)node*DP + q*8];
      uint4 x1 = *(const uint4*)&base1[(size_t)node*DP + q*8];
      A0[0]=sv*up2(x0.x); A0[1]=sv*up2(x0.y); A0[2]=sv*up2(x0.z); A0[3]=sv*up2(x0.w);
      A1[0]=sv*up2(x1.x); A1[1]=sv*up2(x1.y); A1[2]=sv*up2(x1.z); A1[3]=sv*up2(x1.w);
    }
    const int e1 = off[node+1];
    int e = off[node] + slot;
    for(; e+8<e1; e+=16){
      int s0=srcs[e], s1=srcs[e+8];
      uint4 xa0=*(const uint4*)&base0[(size_t)s0*DP + q*8];
      uint4 xb0=*(const uint4*)&base1[(size_t)s0*DP + q*8];
      uint4 xa1=*(const uint4*)&base0[(size_t)s1*DP + q*8];
      uint4 xb1=*(const uint4*)&base1[(size_t)s1*DP + q*8];
      accp8(A0,xa0); accp8(A1,xb0); accp8(A0,xa1); accp8(A1,xb1);
    }
    if(e<e1){
      int s0=srcs[e];
      uint4 xa0=*(const uint4*)&base0[(size_t)s0*DP + q*8];
      uint4 xb0=*(const uint4*)&base1[(size_t)s0*DP + q*8];
      accp8(A0,xa0); accp8(A1,xb0);
    }
    #pragma unroll
    for(int d2=8; d2<64; d2<<=1){
      #pragma unroll
      for(int i=0;i<4;++i){
        A0[i].x+=__shfl_xor(A0[i].x,d2,64); A0[i].y+=__shfl_xor(A0[i].y,d2,64);
        A1[i].x+=__shfl_xor(A1[i].x,d2,64); A1[i].y+=__shfl_xor(A1[i].y,d2,64);
      }
    }
    if(l<8){
      uint4 o0; o0.x=pk2(A0[0].x,A0[0].y); o0.y=pk2(A0[1].x,A0[1].y);
                o0.z=pk2(A0[2].x,A0[2].y); o0.w=pk2(A0[3].x,A0[3].y);
      uint4 o1; o1.x=pk2(A1[0].x,A1[0].y); o1.y=pk2(A1[1].x,A1[1].y);
                o1.z=pk2(A1[2].x,A1[2].y); o1.w=pk2(A1[3].x,A1[3].y);
      *(uint4*)&zS[w][(nl*2+0)*72 + l*8] = o0;
      *(uint4*)&zS[w][(nl*2+1)*72 + l*8] = o1;
    }
  }

  for(int tt=0; tt<2; ++tt){
    bf16x8 a0 = *(const bf16x8*)&zS[w][(tt*16+col)*72 + quad*8];
    bf16x8 a1 = *(const bf16x8*)&zS[w][(tt*16+col)*72 + 32 + quad*8];
    #pragma unroll
    for(int nt=0;nt<4;++nt){
      f32x4 c; c[0]=bav[nt]; c[1]=bav[nt]; c[2]=bav[nt]; c[3]=bav[nt];
      c = MFMA16(a0, fa[nt][0], c);
      c = MFMA16(a1, fa[nt][1], c);
      #pragma unroll
      for(int r=0;r<4;++r)
        tS[w][(quad*4+r)*68 + nt*16 + col] = fmaxf(c[r], 0.f);
    }
    bf16x8 ta0 = afragT(&tS[w][col*68 + quad*8]);
    bf16x8 ta1 = afragT(&tS[w][col*68 + 32 + quad*8]);
    #pragma unroll
    for(int nt=0;nt<4;++nt){
      f32x4 c; c[0]=bbv[nt]; c[1]=bbv[nt]; c[2]=bbv[nt]; c[3]=bbv[nt];
      c = MFMA16(ta0, fb[nt][0], c);
      c = MFMA16(ta1, fb[nt][1], c);
      float s01 = fmaxf(c[0],0.f)+fmaxf(c[1],0.f);   // rows 4q,4q+1 = node, m-pair
      float s23 = fmaxf(c[2],0.f)+fmaxf(c[3],0.f);   // rows 4q+2,4q+3 = node+1
      const int n0 = nbase + tt*8 + quad*2;
      atomicAdd(&out[(size_t)n0*DP + nt*16 + col], s01);
      atomicAdd(&out[(size_t)(n0+1)*DP + nt*16 + col], s23);
    }
  }
}

extern "C" void kernel_launch(void* const* d_in, const int* in_sizes, int n_in,
                              void* d_out, int out_size, void* d_ws, size_t ws_size,
                              hipStream_t stream)
{
  (void)in_sizes; (void)n_in; (void)out_size; (void)ws_size;
  const float* lap  = (const float*)d_in[0];
  const float* W0   = (const float*)d_in[1];
  const float* mlpW = (const float*)d_in[2];
  // d_in[3] = mlp_b: cancels inside BatchNorm (pure mean shift)
  const float* bng  = (const float*)d_in[4];
  const float* bnb  = (const float*)d_in[5];
  const float* eps1 = (const float*)d_in[6];
  const float* W1a  = (const float*)d_in[7];
  const float* b1a  = (const float*)d_in[8];
  const float* W1b  = (const float*)d_in[9];
  const float* b1b  = (const float*)d_in[10];
  const float* eps2 = (const float*)d_in[11];
  const float* W2a  = (const float*)d_in[12];
  const float* b2a  = (const float*)d_in[13];
  const float* W2b  = (const float*)d_in[14];
  const float* b2b  = (const float*)d_in[15];
  const int*   ei   = (const int*)d_in[16];
  const int* srcI = ei;
  const int* dstI = ei + NE;

  char* ws = (char*)d_ws;
  u16* h1T  = (u16*)(ws);                    //  8,388,608 B  [16][16384][16]
  u16* h2T  = (u16*)(ws + 8388608);          // 33,554,432 B  [16][16384][64]
  int* cnt  = (int*)(ws + 41943040);         //     65,536 B
  int* offA = (int*)(ws + 42008576);         //     65,792 B (NSUM+1)
  int* wpos = (int*)(ws + 42074368);         //     65,536 B
  int* srcs = (int*)(ws + 42139904);         //  1,048,576 B  (end 43,188,480)

  k_poly   <<<BG,      512, 0, stream>>>(lap, W0, mlpW, bng, bnb, h1T, cnt);
  k_hist   <<<NE/256,  256, 0, stream>>>(dstI, cnt);
  k_scan   <<<1,       256, 0, stream>>>(cnt, offA, wpos);
  k_scatter<<<NE/256,  256, 0, stream>>>(srcI, dstI, wpos, srcs, (float4*)d_out);
  k_gin1f  <<<8*(NSUM/64), 256, 0, stream>>>(h1T, W1a, b1a, W1b, b1b, eps1, offA, srcs, h2T);
  k_gin2f  <<<8*(NSUM/64), 256, 0, stream>>>(h2T, W2a, b2a, W2b, b2b, eps2, offA, srcs, (float*)d_out);
}

// Round 9
// 338.346 us; speedup vs baseline: 1.3621x; 1.3621x over previous
//
#include <hip/hip_runtime.h>

typedef unsigned short u16;
typedef unsigned int   u32;
typedef short bf16x8 __attribute__((ext_vector_type(8)));
typedef float f32x4  __attribute__((ext_vector_type(4)));

#define BG    128      // graphs
#define NN    128      // nodes per graph
#define MS    16       // samples
#define KP    8        // pearl_k
#define HM    16       // mlp hidden
#define DP    64       // pe dims
#define NSUM  16384    // BG*NN
#define NE    262144   // edges
#define SITES 2048     // NN*MS

// R3: inputs f32, output f32. Intermediates bf16.
// R5 = empirical best structure (297us): row-major gathers, persistent lane
//   column-ownership (NO shuffle epilogue), batch-8 loads; MFMA mm kernels.
// R6 (m-sliced dword): 108us issue-bound. R7 (m-sliced fat): 86us VALU-bound
//   on slot-reduce epilogue. R8 (fused): 169us occupancy-starved. All REVERTED.
// R9: R5 + poly@512 + cnt-fold + agg1/agg2 split in half (diagnostic: let the
//   #2 kernel surface in top-5; top-5 otherwise fills with 5 replay clones).

__device__ __forceinline__ float blo(u32 u){ union{u32 i; float f;} v; v.i=u<<16; return v.f; }
__device__ __forceinline__ float bhi(u32 u){ union{u32 i; float f;} v; v.i=u&0xffff0000u; return v.f; }
__device__ __forceinline__ u16  f2b(float f){ union{float f; u32 i;} v; v.f=f; u32 x=v.i; x += 0x7fffu + ((x>>16)&1u); return (u16)(x>>16); }
__device__ __forceinline__ u32  pk2(float a, float b){ return (u32)f2b(a) | ((u32)f2b(b)<<16); }

__device__ __forceinline__ void acc4s(float* a, uint2 x, float s){
  a[0]+=s*blo(x.x); a[1]+=s*bhi(x.x); a[2]+=s*blo(x.y); a[3]+=s*bhi(x.y);
}
__device__ __forceinline__ void acc16s(float* a, uint4 x0, uint4 x1, float s){
  a[0] +=s*blo(x0.x); a[1] +=s*bhi(x0.x); a[2] +=s*blo(x0.y); a[3] +=s*bhi(x0.y);
  a[4] +=s*blo(x0.z); a[5] +=s*bhi(x0.z); a[6] +=s*blo(x0.w); a[7] +=s*bhi(x0.w);
  a[8] +=s*blo(x1.x); a[9] +=s*bhi(x1.x); a[10]+=s*blo(x1.y); a[11]+=s*bhi(x1.y);
  a[12]+=s*blo(x1.z); a[13]+=s*bhi(x1.z); a[14]+=s*blo(x1.w); a[15]+=s*bhi(x1.w);
}

#define MFMA16(a,b,c) __builtin_amdgcn_mfma_f32_16x16x32_bf16(a,b,c,0,0,0)

__device__ __forceinline__ bf16x8 bfragW(const float* __restrict__ W, int nrows,
                                         int k0, int nb, int col, int quad){
  bf16x8 f;
  #pragma unroll
  for(int j=0;j<8;++j){
    int k = k0 + quad*8 + j;
    float v = (k < nrows) ? W[k*DP + nb + col] : 0.f;
    f[j] = (short)f2b(v);
  }
  return f;
}
__device__ __forceinline__ bf16x8 afragT(const float* tp){
  float4 v0 = *(const float4*)tp;
  float4 v1 = *(const float4*)(tp+4);
  bf16x8 a;
  a[0]=(short)f2b(v0.x); a[1]=(short)f2b(v0.y); a[2]=(short)f2b(v0.z); a[3]=(short)f2b(v0.w);
  a[4]=(short)f2b(v1.x); a[5]=(short)f2b(v1.y); a[6]=(short)f2b(v1.z); a[7]=(short)f2b(v1.w);
  return a;
}

// ---------------------------------------------------------------------------
// K1: per-graph polynomial filter + MLP over k + BN + ReLU. 512 threads
// (thread owns n, 4 m's). Also zeroes cnt[]. h1 row-major [node][m][c] bf16.
// mlp_b skipped (cancels in BN mean-subtract).
// ---------------------------------------------------------------------------
__global__ __launch_bounds__(512) void k_poly(
    const float* __restrict__ lap, const float* __restrict__ W0, const float* __restrict__ mlpW,
    const float* __restrict__ bng, const float* __restrict__ bnb, u16* __restrict__ h1,
    int* __restrict__ cnt)
{
  __shared__ float Wbuf[2][SITES];   // 16 KB
  __shared__ float mlpWS[KP*HM];
  __shared__ float red[8][32];
  __shared__ float stat[32];
  __shared__ float ssc[HM], ssh[HM];

  const int b = blockIdx.x, t = threadIdx.x;
  {
    int gi = b*512 + t;
    if (gi < NSUM) cnt[gi] = 0;
  }
  for (int i=t; i<SITES; i+=512) Wbuf[0][i] = W0[(size_t)b*SITES+i];
  if (t < KP*HM) mlpWS[t] = mlpW[t];
  __syncthreads();

  const int n = t>>2, m0 = (t&3)*4;      // thread owns sites (n, m0..m0+3)
  float h[4][16];
  {
    float mw[16];
    #pragma unroll
    for(int c=0;c<16;++c) mw[c]=mlpWS[c];
    #pragma unroll
    for(int si=0;si<4;++si){
      float f0 = Wbuf[0][n*MS+m0+si];
      #pragma unroll
      for(int c=0;c<16;++c) h[si][c] = f0*mw[c];
    }
  }
  int cur=0;
  const float* lgf = lap + (size_t)b*NN*NN + (size_t)n*NN;
  for(int k=1;k<KP;++k){
    float acc[4] = {0.f,0.f,0.f,0.f};
    const float* wb = &Wbuf[cur][m0];
    for(int j=0;j<NN;j+=2){
      float2 lv = *(const float2*)&lgf[j];
      float a0 = lv.x, a1 = lv.y;
      float4 w0 = *(const float4*)&wb[j*MS];
      float4 w1 = *(const float4*)&wb[(j+1)*MS];
      acc[0]+=a0*w0.x; acc[1]+=a0*w0.y; acc[2]+=a0*w0.z; acc[3]+=a0*w0.w;
      acc[0]+=a1*w1.x; acc[1]+=a1*w1.y; acc[2]+=a1*w1.z; acc[3]+=a1*w1.w;
    }
    __syncthreads();
    {
      float4 av; av.x=acc[0]; av.y=acc[1]; av.z=acc[2]; av.w=acc[3];
      *(float4*)&Wbuf[cur^1][n*MS+m0] = av;
      float mw[16];
      #pragma unroll
      for(int c=0;c<16;++c) mw[c]=mlpWS[k*16+c];
      #pragma unroll
      for(int si=0;si<4;++si){
        #pragma unroll
        for(int c=0;c<16;++c) h[si][c] += acc[si]*mw[c];
      }
    }
    __syncthreads();
    cur ^= 1;
  }
  float sum[16], sq[16];
  #pragma unroll
  for(int c=0;c<16;++c){ sum[c]=0.f; sq[c]=0.f; }
  #pragma unroll
  for(int si=0;si<4;++si){
    #pragma unroll
    for(int c=0;c<16;++c){ float v=h[si][c]; sum[c]+=v; sq[c]+=v*v; }
  }
  #pragma unroll
  for(int d=1;d<64;d<<=1){
    #pragma unroll
    for(int c=0;c<16;++c){ sum[c]+=__shfl_xor(sum[c],d,64); sq[c]+=__shfl_xor(sq[c],d,64); }
  }
  const int lane=t&63, wid=t>>6;
  if(lane==0){
    #pragma unroll
    for(int c=0;c<16;++c){ red[wid][c]=sum[c]; red[wid][16+c]=sq[c]; }
  }
  __syncthreads();
  if(t<32){
    float s=0.f;
    #pragma unroll
    for(int ww=0;ww<8;++ww) s += red[ww][t];
    stat[t]=s;
  }
  __syncthreads();
  if(t<16){
    float mu  = stat[t]*(1.f/SITES);
    float var = stat[16+t]*(1.f/SITES) - mu*mu;
    float sc  = bng[t] * rsqrtf(var + 1e-5f);
    ssc[t]=sc; ssh[t]=bnb[t] - mu*sc;
  }
  __syncthreads();
  {
    const int node = b*NN + n;
    float sc[16], sh[16];
    #pragma unroll
    for(int c=0;c<16;++c){ sc[c]=ssc[c]; sh[c]=ssh[c]; }
    #pragma unroll
    for(int si=0;si<4;++si){
      float r[16];
      #pragma unroll
      for(int c=0;c<16;++c) r[c]=fmaxf(h[si][c]*sc[c]+sh[c], 0.f);
      uint4 A;
      A.x=pk2(r[0],r[1]);  A.y=pk2(r[2],r[3]);  A.z=pk2(r[4],r[5]);  A.w=pk2(r[6],r[7]);
      uint4 Bv;
      Bv.x=pk2(r[8],r[9]); Bv.y=pk2(r[10],r[11]); Bv.z=pk2(r[12],r[13]); Bv.w=pk2(r[14],r[15]);
      u16* o = h1 + (size_t)node*256 + (size_t)(m0+si)*HM;
      *(uint4*)o     = A;
      *(uint4*)(o+8) = Bv;
    }
  }
}

// --------------------------- CSR build (by dst) ----------------------------
__global__ void k_hist(const int* __restrict__ dst, int* __restrict__ cnt){
  int e = blockIdx.x*256 + threadIdx.x;
  atomicAdd(&cnt[dst[e]], 1);
}

__global__ void k_scan(const int* __restrict__ cnt, int* __restrict__ off, int* __restrict__ wpos){
  __shared__ int ps[256];
  const int t = threadIdx.x, PER = NSUM/256;
  int s=0;
  for(int i=0;i<PER;++i) s += cnt[t*PER+i];
  ps[t]=s; __syncthreads();
  for(int d=1; d<256; d<<=1){
    int v = (t>=d) ? ps[t-d] : 0;
    __syncthreads();
    ps[t] += v;
    __syncthreads();
  }
  int run = (t==0) ? 0 : ps[t-1];
  for(int i=0;i<PER;++i){
    int idx=t*PER+i;
    off[idx]=run; wpos[idx]=run;
    run += cnt[idx];
  }
  if(t==255) off[NSUM]=run;
}

__global__ void k_scatter(const int* __restrict__ srcI, const int* __restrict__ dstI,
                          int* __restrict__ wpos, int* __restrict__ srcs){
  int e = blockIdx.x*256 + threadIdx.x;
  int p = atomicAdd(&wpos[dstI[e]], 1);
  srcs[p] = srcI[e];
}

// ---------------------------------------------------------------------------
// K4a: GIN-1 aggregate (R5 structure). 1 node/wave, no LDS, persistent lane
// ownership (lane l owns flat elems [4l,4l+4)), batch-of-8 dwordx2.
// ---------------------------------------------------------------------------
__global__ __launch_bounds__(256) void k_agg1(
  const u16* __restrict__ h1, const float* __restrict__ eps1p,
  const int* __restrict__ off, const int* __restrict__ srcs, u16* __restrict__ z1,
  int nodeBase)
{
  const int t=threadIdx.x, l=t&63;
  const int node = nodeBase + blockIdx.x*4 + (t>>6);
  const float epe = 1.f + eps1p[0];
  float a[4] = {0.f,0.f,0.f,0.f};
  acc4s(a, *(const uint2*)&h1[(size_t)node*256 + l*4], epe);
  int e=off[node]; const int e1=off[node+1];
  for(; e+8<=e1; e+=8){
    int s0=srcs[e],s1=srcs[e+1],s2=srcs[e+2],s3=srcs[e+3];
    int s4=srcs[e+4],s5=srcs[e+5],s6=srcs[e+6],s7=srcs[e+7];
    uint2 r0=*(const uint2*)&h1[(size_t)s0*256 + l*4];
    uint2 r1=*(const uint2*)&h1[(size_t)s1*256 + l*4];
    uint2 r2=*(const uint2*)&h1[(size_t)s2*256 + l*4];
    uint2 r3=*(const uint2*)&h1[(size_t)s3*256 + l*4];
    uint2 r4=*(const uint2*)&h1[(size_t)s4*256 + l*4];
    uint2 r5=*(const uint2*)&h1[(size_t)s5*256 + l*4];
    uint2 r6=*(const uint2*)&h1[(size_t)s6*256 + l*4];
    uint2 r7=*(const uint2*)&h1[(size_t)s7*256 + l*4];
    acc4s(a,r0,1.f); acc4s(a,r1,1.f); acc4s(a,r2,1.f); acc4s(a,r3,1.f);
    acc4s(a,r4,1.f); acc4s(a,r5,1.f); acc4s(a,r6,1.f); acc4s(a,r7,1.f);
  }
  for(; e<e1; ++e){
    uint2 r=*(const uint2*)&h1[(size_t)srcs[e]*256 + l*4];
    acc4s(a,r,1.f);
  }
  uint2 o; o.x=pk2(a[0],a[1]); o.y=pk2(a[2],a[3]);
  *(uint2*)&z1[(size_t)node*256 + l*4] = o;
}

// ---------------------------------------------------------------------------
// K5a: GIN-2 aggregate (R5 structure). 1 node/wave, lane owns [16l,16l+16),
// batch-of-8 (16 dwordx4 in flight).
// ---------------------------------------------------------------------------
__global__ __launch_bounds__(256) void k_agg2(
  const u16* __restrict__ h2, const float* __restrict__ eps2p,
  const int* __restrict__ off, const int* __restrict__ srcs, u16* __restrict__ z2,
  int nodeBase)
{
  const int t=threadIdx.x, l=t&63;
  const int node = nodeBase + blockIdx.x*4 + (t>>6);
  const float epe = 1.f + eps2p[0];
  float a[16];
  #pragma unroll
  for(int i=0;i<16;++i) a[i]=0.f;
  {
    const uint4* r=(const uint4*)&h2[(size_t)node*1024 + l*16];
    acc16s(a, r[0], r[1], epe);
  }
  int e=off[node]; const int e1=off[node+1];
  for(; e+8<=e1; e+=8){
    int s0=srcs[e],s1=srcs[e+1],s2=srcs[e+2],s3=srcs[e+3];
    int s4=srcs[e+4],s5=srcs[e+5],s6=srcs[e+6],s7=srcs[e+7];
    const uint4* r0=(const uint4*)&h2[(size_t)s0*1024 + l*16];
    const uint4* r1=(const uint4*)&h2[(size_t)s1*1024 + l*16];
    const uint4* r2=(const uint4*)&h2[(size_t)s2*1024 + l*16];
    const uint4* r3=(const uint4*)&h2[(size_t)s3*1024 + l*16];
    const uint4* r4=(const uint4*)&h2[(size_t)s4*1024 + l*16];
    const uint4* r5=(const uint4*)&h2[(size_t)s5*1024 + l*16];
    const uint4* r6=(const uint4*)&h2[(size_t)s6*1024 + l*16];
    const uint4* r7=(const uint4*)&h2[(size_t)s7*1024 + l*16];
    uint4 a0=r0[0],b0=r0[1], a1=r1[0],b1=r1[1], a2=r2[0],b2=r2[1], a3=r3[0],b3=r3[1];
    uint4 a4=r4[0],b4=r4[1], a5=r5[0],b5=r5[1], a6=r6[0],b6=r6[1], a7=r7[0],b7=r7[1];
    acc16s(a,a0,b0,1.f); acc16s(a,a1,b1,1.f); acc16s(a,a2,b2,1.f); acc16s(a,a3,b3,1.f);
    acc16s(a,a4,b4,1.f); acc16s(a,a5,b5,1.f); acc16s(a,a6,b6,1.f); acc16s(a,a7,b7,1.f);
  }
  for(; e<e1; ++e){
    const uint4* r=(const uint4*)&h2[(size_t)srcs[e]*1024 + l*16];
    acc16s(a, r[0], r[1], 1.f);
  }
  uint4 o0, o1;
  o0.x=pk2(a[0],a[1]);   o0.y=pk2(a[2],a[3]);   o0.z=pk2(a[4],a[5]);   o0.w=pk2(a[6],a[7]);
  o1.x=pk2(a[8],a[9]);   o1.y=pk2(a[10],a[11]); o1.z=pk2(a[12],a[13]); o1.w=pk2(a[14],a[15]);
  uint4* zp = (uint4*)&z2[(size_t)node*1024 + l*16];
  zp[0]=o0; zp[1]=o1;
}

// ---------------------------------------------------------------------------
// K4b: GIN-1 MLP via MFMA (R5). z1 K zero-padded to 32; h2 row-major bf16.
// ---------------------------------------------------------------------------
__global__ __launch_bounds__(256) void k_mm1(
  const u16* __restrict__ z1, const float* __restrict__ W1a, const float* __restrict__ b1a,
  const float* __restrict__ W1b, const float* __restrict__ b1b, u16* __restrict__ h2)
{
  __shared__ float tS[4][16*68 + 4];        // 17.5 KB, per-wave slices
  const int t=threadIdx.x, l=t&63, w=t>>6;
  const int col=l&15, quad=l>>4;

  bf16x8 fa[4], fb[4][2];
  float bav[4], bbv[4];
  #pragma unroll
  for(int nt=0;nt<4;++nt){
    fa[nt]    = bfragW(W1a, HM, 0,  nt*16, col, quad);   // k>=16 zeroed
    fb[nt][0] = bfragW(W1b, DP, 0,  nt*16, col, quad);
    fb[nt][1] = bfragW(W1b, DP, 32, nt*16, col, quad);
    bav[nt] = b1a[nt*16+col];
    bbv[nt] = b1b[nt*16+col];
  }
  for(int ni=0;ni<2;++ni){
    const int node = blockIdx.x*8 + ni*4 + w;
    bf16x8 a0;
    #pragma unroll
    for(int j=0;j<8;++j) a0[j]=0;
    if (quad < 2) a0 = *(const bf16x8*)&z1[(size_t)node*256 + col*16 + quad*8];
    #pragma unroll
    for(int nt=0;nt<4;++nt){
      f32x4 c = {bav[nt], bav[nt], bav[nt], bav[nt]};
      c = MFMA16(a0, fa[nt], c);
      #pragma unroll
      for(int r=0;r<4;++r)
        tS[w][(quad*4+r)*68 + nt*16 + col] = fmaxf(c[r], 0.f);
    }
    bf16x8 ta0 = afragT(&tS[w][col*68 + quad*8]);
    bf16x8 ta1 = afragT(&tS[w][col*68 + 32 + quad*8]);
    #pragma unroll
    for(int nt=0;nt<4;++nt){
      f32x4 c = {bbv[nt], bbv[nt], bbv[nt], bbv[nt]};
      c = MFMA16(ta0, fb[nt][0], c);
      c = MFMA16(ta1, fb[nt][1], c);
      #pragma unroll
      for(int r=0;r<4;++r)
        h2[(size_t)node*1024 + (quad*4+r)*64 + nt*16 + col] = f2b(fmaxf(c[r], 0.f));
    }
  }
}

// ---------------------------------------------------------------------------
// K5b: GIN-2 MLP via MFMA + ReLU + sum over M -> out f32 [NSUM,64]. (R5)
// ---------------------------------------------------------------------------
__global__ __launch_bounds__(256) void k_mm2(
  const u16* __restrict__ z2, const float* __restrict__ W2a, const float* __restrict__ b2a,
  const float* __restrict__ W2b, const float* __restrict__ b2b, float* __restrict__ out)
{
  __shared__ float tS[4][16*68 + 4];
  const int t=threadIdx.x, l=t&63, w=t>>6;
  const int col=l&15, quad=l>>4;

  bf16x8 fa[4][2], fb[4][2];
  float bav[4], bbv[4];
  #pragma unroll
  for(int nt=0;nt<4;++nt){
    fa[nt][0] = bfragW(W2a, DP, 0,  nt*16, col, quad);
    fa[nt][1] = bfragW(W2a, DP, 32, nt*16, col, quad);
    fb[nt][0] = bfragW(W2b, DP, 0,  nt*16, col, quad);
    fb[nt][1] = bfragW(W2b, DP, 32, nt*16, col, quad);
    bav[nt] = b2a[nt*16+col];
    bbv[nt] = b2b[nt*16+col];
  }
  for(int ni=0;ni<2;++ni){
    const int node = blockIdx.x*8 + ni*4 + w;
    const u16* zrow = &z2[(size_t)node*1024];
    bf16x8 a0 = *(const bf16x8*)&zrow[col*64 + quad*8];
    bf16x8 a1 = *(const bf16x8*)&zrow[col*64 + quad*8 + 32];
    #pragma unroll
    for(int nt=0;nt<4;++nt){
      f32x4 c = {bav[nt], bav[nt], bav[nt], bav[nt]};
      c = MFMA16(a0, fa[nt][0], c);
      c = MFMA16(a1, fa[nt][1], c);
      #pragma unroll
      for(int r=0;r<4;++r)
        tS[w][(quad*4+r)*68 + nt*16 + col] = fmaxf(c[r], 0.f);
    }
    bf16x8 ta0 = afragT(&tS[w][col*68 + quad*8]);
    bf16x8 ta1 = afragT(&tS[w][col*68 + 32 + quad*8]);
    #pragma unroll
    for(int nt=0;nt<4;++nt){
      f32x4 c = {bbv[nt], bbv[nt], bbv[nt], bbv[nt]};
      c = MFMA16(ta0, fb[nt][0], c);
      c = MFMA16(ta1, fb[nt][1], c);
      float s = fmaxf(c[0],0.f)+fmaxf(c[1],0.f)+fmaxf(c[2],0.f)+fmaxf(c[3],0.f);
      s += __shfl_xor(s, 16, 64);
      s += __shfl_xor(s, 32, 64);
      if (quad == 0)
        out[(size_t)node*64 + nt*16 + col] = s;
    }
  }
}

extern "C" void kernel_launch(void* const* d_in, const int* in_sizes, int n_in,
                              void* d_out, int out_size, void* d_ws, size_t ws_size,
                              hipStream_t stream)
{
  (void)in_sizes; (void)n_in; (void)out_size; (void)ws_size;
  const float* lap  = (const float*)d_in[0];
  const float* W0   = (const float*)d_in[1];
  const float* mlpW = (const float*)d_in[2];
  // d_in[3] = mlp_b: cancels inside BatchNorm (pure mean shift)
  const float* bng  = (const float*)d_in[4];
  const float* bnb  = (const float*)d_in[5];
  const float* eps1 = (const float*)d_in[6];
  const float* W1a  = (const float*)d_in[7];
  const float* b1a  = (const float*)d_in[8];
  const float* W1b  = (const float*)d_in[9];
  const float* b1b  = (const float*)d_in[10];
  const float* eps2 = (const float*)d_in[11];
  const float* W2a  = (const float*)d_in[12];
  const float* b2a  = (const float*)d_in[13];
  const float* W2b  = (const float*)d_in[14];
  const float* b2b  = (const float*)d_in[15];
  const int*   ei   = (const int*)d_in[16];
  const int* srcI = ei;
  const int* dstI = ei + NE;

  char* ws = (char*)d_ws;
  u16* h1   = (u16*)(ws);                    //  8,388,608 B  [16384][16][16]
  u16* z1   = (u16*)(ws + 8388608);          //  8,388,608 B
  u16* h2   = (u16*)(ws + 16777216);         // 33,554,432 B  [16384][16][64]
  u16* z2   = (u16*)(ws + 50331648);         // 33,554,432 B
  int* cnt  = (int*)(ws + 83886080);         //     65,536 B
  int* offA = (int*)(ws + 83951616);         //     65,792 B
  int* wpos = (int*)(ws + 84017408);         //     65,536 B
  int* srcs = (int*)(ws + 84082944);         //  1,048,576 B  (end 85,131,520)

  k_poly   <<<BG,      512, 0, stream>>>(lap, W0, mlpW, bng, bnb, h1, cnt);
  k_hist   <<<NE/256,  256, 0, stream>>>(dstI, cnt);
  k_scan   <<<1,       256, 0, stream>>>(cnt, offA, wpos);
  k_scatter<<<NE/256,  256, 0, stream>>>(srcI, dstI, wpos, srcs);
  k_agg1   <<<NSUM/8,  256, 0, stream>>>(h1, eps1, offA, srcs, z1, 0);
  k_agg1   <<<NSUM/8,  256, 0, stream>>>(h1, eps1, offA, srcs, z1, NSUM/2);
  k_mm1    <<<NSUM/8,  256, 0, stream>>>(z1, W1a, b1a, W1b, b1b, h2);
  k_agg2   <<<NSUM/8,  256, 0, stream>>>(h2, eps2, offA, srcs, z2, 0);
  k_agg2   <<<NSUM/8,  256, 0, stream>>>(h2, eps2, offA, srcs, z2, NSUM/2);
  k_mm2    <<<NSUM/8,  256, 0, stream>>>(z2, W2a, b2a, W2b, b2b, (float*)d_out);
}

// Round 10
// 282.045 us; speedup vs baseline: 1.6340x; 1.1996x over previous
//
#include <hip/hip_runtime.h>

typedef unsigned short u16;
typedef unsigned int   u32;
typedef short bf16x8 __attribute__((ext_vector_type(8)));
typedef float f32x4  __attribute__((ext_vector_type(4)));

#define BG    128      // graphs
#define NN    128      // nodes per graph
#define MS    16       // samples
#define KP    8        // pearl_k
#define HM    16       // mlp hidden
#define DP    64       // pe dims
#define NSUM  16384    // BG*NN
#define NE    262144   // edges
#define SITES 2048     // NN*MS

// R3: inputs f32, output f32. Intermediates bf16.
// R5 structure = empirical best for gather/mm (297us).
// R9 diagnostic: k_poly was the hidden #1 (67us hot/172 cold, VALUBusy 6% ->
//   global-latency chain on lap reads).
// R10: k_poly rewritten as MFMA hi/lo-bf16 split-precision recurrence:
//   lap A-frags live in registers (loaded once), W_k state stays f32 in LDS,
//   3 MFMAs per tile (AhBh+AhBl+AlBh) ~= f32 precision, 1 barrier per hop.

__device__ __forceinline__ float blo(u32 u){ union{u32 i; float f;} v; v.i=u<<16; return v.f; }
__device__ __forceinline__ float bhi(u32 u){ union{u32 i; float f;} v; v.i=u&0xffff0000u; return v.f; }
__device__ __forceinline__ u16  f2b(float f){ union{float f; u32 i;} v; v.f=f; u32 x=v.i; x += 0x7fffu + ((x>>16)&1u); return (u16)(x>>16); }
__device__ __forceinline__ u32  pk2(float a, float b){ return (u32)f2b(a) | ((u32)f2b(b)<<16); }

__device__ __forceinline__ void fsplit(float x, short& hi, short& lo){
  u16 h = f2b(x); hi = (short)h; lo = (short)f2b(x - blo((u32)h));
}

__device__ __forceinline__ void acc4s(float* a, uint2 x, float s){
  a[0]+=s*blo(x.x); a[1]+=s*bhi(x.x); a[2]+=s*blo(x.y); a[3]+=s*bhi(x.y);
}
__device__ __forceinline__ void acc16s(float* a, uint4 x0, uint4 x1, float s){
  a[0] +=s*blo(x0.x); a[1] +=s*bhi(x0.x); a[2] +=s*blo(x0.y); a[3] +=s*bhi(x0.y);
  a[4] +=s*blo(x0.z); a[5] +=s*bhi(x0.z); a[6] +=s*blo(x0.w); a[7] +=s*bhi(x0.w);
  a[8] +=s*blo(x1.x); a[9] +=s*bhi(x1.x); a[10]+=s*blo(x1.y); a[11]+=s*bhi(x1.y);
  a[12]+=s*blo(x1.z); a[13]+=s*bhi(x1.z); a[14]+=s*blo(x1.w); a[15]+=s*bhi(x1.w);
}

#define MFMA16(a,b,c) __builtin_amdgcn_mfma_f32_16x16x32_bf16(a,b,c,0,0,0)

__device__ __forceinline__ bf16x8 bfragW(const float* __restrict__ W, int nrows,
                                         int k0, int nb, int col, int quad){
  bf16x8 f;
  #pragma unroll
  for(int j=0;j<8;++j){
    int k = k0 + quad*8 + j;
    float v = (k < nrows) ? W[k*DP + nb + col] : 0.f;
    f[j] = (short)f2b(v);
  }
  return f;
}
__device__ __forceinline__ bf16x8 afragT(const float* tp){
  float4 v0 = *(const float4*)tp;
  float4 v1 = *(const float4*)(tp+4);
  bf16x8 a;
  a[0]=(short)f2b(v0.x); a[1]=(short)f2b(v0.y); a[2]=(short)f2b(v0.z); a[3]=(short)f2b(v0.w);
  a[4]=(short)f2b(v1.x); a[5]=(short)f2b(v1.y); a[6]=(short)f2b(v1.z); a[7]=(short)f2b(v1.w);
  return a;
}

// ---------------------------------------------------------------------------
// K1: poly filter via MFMA split-precision. Block=graph (256 thr, 4 waves).
// Wave w owns n-rows [w*32, w*32+32) = 2 M-tiles. A = lap rows (hi/lo bf16
// frags in regs, loaded once). B = W_k [128][16] f32 in LDS (split at read).
// out[n][m] = sum_j lap[n][j] W_k[j][m]; h[site][c] += out * mlpW[k][c];
// then BN + ReLU -> h1 [node][m][c] bf16. mlp_b cancels in BN.
// ---------------------------------------------------------------------------
__global__ __launch_bounds__(256,1) void k_poly(
    const float* __restrict__ lap, const float* __restrict__ W0, const float* __restrict__ mlpW,
    const float* __restrict__ bng, const float* __restrict__ bnb, u16* __restrict__ h1,
    int* __restrict__ cnt)
{
  __shared__ float Wbuf[2][SITES];   // 2 x 8 KB : W_k state (f32!)
  __shared__ float mlpWS[KP*HM];
  __shared__ float red[4][32];
  __shared__ float stat[32];
  __shared__ float ssc[HM], ssh[HM];

  const int b = blockIdx.x, t = threadIdx.x, l = t&63, w = t>>6;
  const int col = l&15, quad = l>>4;
  if (t < 128) cnt[b*128 + t] = 0;

  // stage W0 -> Wbuf[0] (coalesced), mlpW -> LDS
  {
    const float4* src = (const float4*)(W0 + (size_t)b*SITES);
    for (int i=t; i<SITES/4; i+=256) ((float4*)Wbuf[0])[i] = src[i];
    if (t < KP*HM) mlpWS[t] = mlpW[t];
  }

  // A-frags: lap rows, hi/lo split, in registers. Mt in {0,1}, Kc in {0..3}.
  bf16x8 Ah[2][4], Al[2][4];
  {
    const float* lg = lap + (size_t)b*NN*NN;
    #pragma unroll
    for(int Mt=0;Mt<2;++Mt){
      const int nr = w*32 + Mt*16 + col;
      #pragma unroll
      for(int Kc=0;Kc<4;++Kc){
        const float* p = lg + (size_t)nr*NN + Kc*32 + quad*8;
        float4 v0 = *(const float4*)p;
        float4 v1 = *(const float4*)(p+4);
        float xs[8] = {v0.x,v0.y,v0.z,v0.w,v1.x,v1.y,v1.z,v1.w};
        #pragma unroll
        for(int j=0;j<8;++j){ short hi,lo; fsplit(xs[j],hi,lo); Ah[Mt][Kc][j]=hi; Al[Mt][Kc][j]=lo; }
      }
    }
  }

  // h init: h[s][c] = W0_site * mlpW[0][c]; site s=Mt*4+r -> n=w*32+Mt*16+quad*4+r, m=col
  float h[8][16];
  {
    const float* w0g = W0 + (size_t)b*SITES;
    #pragma unroll
    for(int Mt=0;Mt<2;++Mt){
      #pragma unroll
      for(int r=0;r<4;++r){
        const int n = w*32 + Mt*16 + quad*4 + r;
        float sv = w0g[n*MS + col];
        #pragma unroll
        for(int c=0;c<16;++c) h[Mt*4+r][c] = sv*mlpW[c];
      }
    }
  }
  __syncthreads();

  int cur=0;
  for(int k=1;k<KP;++k){
    f32x4 c0 = {0.f,0.f,0.f,0.f};
    f32x4 c1 = {0.f,0.f,0.f,0.f};
    #pragma unroll
    for(int Kc=0;Kc<4;++Kc){
      const float* wb = &Wbuf[cur][(Kc*32 + quad*8)*MS + col];
      bf16x8 Bh, Bl;
      #pragma unroll
      for(int j=0;j<8;++j){
        float x = wb[j*MS];
        short hi,lo; fsplit(x,hi,lo); Bh[j]=hi; Bl[j]=lo;
      }
      c0 = MFMA16(Ah[0][Kc], Bh, c0);
      c0 = MFMA16(Ah[0][Kc], Bl, c0);
      c0 = MFMA16(Al[0][Kc], Bh, c0);
      c1 = MFMA16(Ah[1][Kc], Bh, c1);
      c1 = MFMA16(Ah[1][Kc], Bl, c1);
      c1 = MFMA16(Al[1][Kc], Bh, c1);
    }
    // write next-W state (f32) + accumulate h
    float mw[16];
    #pragma unroll
    for(int c=0;c<16;++c) mw[c]=mlpWS[k*16+c];
    #pragma unroll
    for(int r=0;r<4;++r){
      const int n0 = w*32 + quad*4 + r;
      Wbuf[cur^1][n0*MS + col]        = c0[r];
      Wbuf[cur^1][(n0+16)*MS + col]   = c1[r];
      #pragma unroll
      for(int c=0;c<16;++c){ h[r][c] += c0[r]*mw[c]; h[4+r][c] += c1[r]*mw[c]; }
    }
    __syncthreads();
    cur ^= 1;
  }

  // BN stats (population mean/var over 2048 sites per channel)
  float sum[16], sq[16];
  #pragma unroll
  for(int c=0;c<16;++c){ sum[c]=0.f; sq[c]=0.f; }
  #pragma unroll
  for(int s=0;s<8;++s){
    #pragma unroll
    for(int c=0;c<16;++c){ float v=h[s][c]; sum[c]+=v; sq[c]+=v*v; }
  }
  #pragma unroll
  for(int d=1;d<64;d<<=1){
    #pragma unroll
    for(int c=0;c<16;++c){ sum[c]+=__shfl_xor(sum[c],d,64); sq[c]+=__shfl_xor(sq[c],d,64); }
  }
  if(l==0){
    #pragma unroll
    for(int c=0;c<16;++c){ red[w][c]=sum[c]; red[w][16+c]=sq[c]; }
  }
  __syncthreads();
  if(t<32) stat[t]=red[0][t]+red[1][t]+red[2][t]+red[3][t];
  __syncthreads();
  if(t<16){
    float mu  = stat[t]*(1.f/SITES);
    float var = stat[16+t]*(1.f/SITES) - mu*mu;
    float sc  = bng[t] * rsqrtf(var + 1e-5f);
    ssc[t]=sc; ssh[t]=bnb[t] - mu*sc;
  }
  __syncthreads();
  {
    float sc[16], sh[16];
    #pragma unroll
    for(int c=0;c<16;++c){ sc[c]=ssc[c]; sh[c]=ssh[c]; }
    #pragma unroll
    for(int s=0;s<8;++s){
      const int n = w*32 + (s>>2)*16 + quad*4 + (s&3);
      const int node = b*NN + n;
      float r[16];
      #pragma unroll
      for(int c=0;c<16;++c) r[c]=fmaxf(h[s][c]*sc[c]+sh[c], 0.f);
      uint4 A;
      A.x=pk2(r[0],r[1]);  A.y=pk2(r[2],r[3]);  A.z=pk2(r[4],r[5]);  A.w=pk2(r[6],r[7]);
      uint4 Bv;
      Bv.x=pk2(r[8],r[9]); Bv.y=pk2(r[10],r[11]); Bv.z=pk2(r[12],r[13]); Bv.w=pk2(r[14],r[15]);
      u16* o = h1 + (size_t)node*256 + (size_t)col*HM;
      *(uint4*)o     = A;
      *(uint4*)(o+8) = Bv;
    }
  }
}

// --------------------------- CSR build (by dst) ----------------------------
__global__ void k_hist(const int* __restrict__ dst, int* __restrict__ cnt){
  int e = blockIdx.x*256 + threadIdx.x;
  atomicAdd(&cnt[dst[e]], 1);
}

__global__ void k_scan(const int* __restrict__ cnt, int* __restrict__ off, int* __restrict__ wpos){
  __shared__ int ps[256];
  const int t = threadIdx.x, PER = NSUM/256;
  int s=0;
  for(int i=0;i<PER;++i) s += cnt[t*PER+i];
  ps[t]=s; __syncthreads();
  for(int d=1; d<256; d<<=1){
    int v = (t>=d) ? ps[t-d] : 0;
    __syncthreads();
    ps[t] += v;
    __syncthreads();
  }
  int run = (t==0) ? 0 : ps[t-1];
  for(int i=0;i<PER;++i){
    int idx=t*PER+i;
    off[idx]=run; wpos[idx]=run;
    run += cnt[idx];
  }
  if(t==255) off[NSUM]=run;
}

__global__ void k_scatter(const int* __restrict__ srcI, const int* __restrict__ dstI,
                          int* __restrict__ wpos, int* __restrict__ srcs){
  int e = blockIdx.x*256 + threadIdx.x;
  int p = atomicAdd(&wpos[dstI[e]], 1);
  srcs[p] = srcI[e];
}

// ---------------------------------------------------------------------------
// K4a: GIN-1 aggregate (R5). 1 node/wave, persistent lane ownership, batch-8.
// ---------------------------------------------------------------------------
__global__ __launch_bounds__(256) void k_agg1(
  const u16* __restrict__ h1, const float* __restrict__ eps1p,
  const int* __restrict__ off, const int* __restrict__ srcs, u16* __restrict__ z1)
{
  const int t=threadIdx.x, l=t&63;
  const int node = blockIdx.x*4 + (t>>6);
  const float epe = 1.f + eps1p[0];
  float a[4] = {0.f,0.f,0.f,0.f};
  acc4s(a, *(const uint2*)&h1[(size_t)node*256 + l*4], epe);
  int e=off[node]; const int e1=off[node+1];
  for(; e+8<=e1; e+=8){
    int s0=srcs[e],s1=srcs[e+1],s2=srcs[e+2],s3=srcs[e+3];
    int s4=srcs[e+4],s5=srcs[e+5],s6=srcs[e+6],s7=srcs[e+7];
    uint2 r0=*(const uint2*)&h1[(size_t)s0*256 + l*4];
    uint2 r1=*(const uint2*)&h1[(size_t)s1*256 + l*4];
    uint2 r2=*(const uint2*)&h1[(size_t)s2*256 + l*4];
    uint2 r3=*(const uint2*)&h1[(size_t)s3*256 + l*4];
    uint2 r4=*(const uint2*)&h1[(size_t)s4*256 + l*4];
    uint2 r5=*(const uint2*)&h1[(size_t)s5*256 + l*4];
    uint2 r6=*(const uint2*)&h1[(size_t)s6*256 + l*4];
    uint2 r7=*(const uint2*)&h1[(size_t)s7*256 + l*4];
    acc4s(a,r0,1.f); acc4s(a,r1,1.f); acc4s(a,r2,1.f); acc4s(a,r3,1.f);
    acc4s(a,r4,1.f); acc4s(a,r5,1.f); acc4s(a,r6,1.f); acc4s(a,r7,1.f);
  }
  for(; e<e1; ++e){
    uint2 r=*(const uint2*)&h1[(size_t)srcs[e]*256 + l*4];
    acc4s(a,r,1.f);
  }
  uint2 o; o.x=pk2(a[0],a[1]); o.y=pk2(a[2],a[3]);
  *(uint2*)&z1[(size_t)node*256 + l*4] = o;
}

// ---------------------------------------------------------------------------
// K5a: GIN-2 aggregate (R5). 1 node/wave, lane owns [16l,16l+16), batch-8.
// ---------------------------------------------------------------------------
__global__ __launch_bounds__(256) void k_agg2(
  const u16* __restrict__ h2, const float* __restrict__ eps2p,
  const int* __restrict__ off, const int* __restrict__ srcs, u16* __restrict__ z2)
{
  const int t=threadIdx.x, l=t&63;
  const int node = blockIdx.x*4 + (t>>6);
  const float epe = 1.f + eps2p[0];
  float a[16];
  #pragma unroll
  for(int i=0;i<16;++i) a[i]=0.f;
  {
    const uint4* r=(const uint4*)&h2[(size_t)node*1024 + l*16];
    acc16s(a, r[0], r[1], epe);
  }
  int e=off[node]; const int e1=off[node+1];
  for(; e+8<=e1; e+=8){
    int s0=srcs[e],s1=srcs[e+1],s2=srcs[e+2],s3=srcs[e+3];
    int s4=srcs[e+4],s5=srcs[e+5],s6=srcs[e+6],s7=srcs[e+7];
    const uint4* r0=(const uint4*)&h2[(size_t)s0*1024 + l*16];
    const uint4* r1=(const uint4*)&h2[(size_t)s1*1024 + l*16];
    const uint4* r2=(const uint4*)&h2[(size_t)s2*1024 + l*16];
    const uint4* r3=(const uint4*)&h2[(size_t)s3*1024 + l*16];
    const uint4* r4=(const uint4*)&h2[(size_t)s4*1024 + l*16];
    const uint4* r5=(const uint4*)&h2[(size_t)s5*1024 + l*16];
    const uint4* r6=(const uint4*)&h2[(size_t)s6*1024 + l*16];
    const uint4* r7=(const uint4*)&h2[(size_t)s7*1024 + l*16];
    uint4 a0=r0[0],b0=r0[1], a1=r1[0],b1=r1[1], a2=r2[0],b2=r2[1], a3=r3[0],b3=r3[1];
    uint4 a4=r4[0],b4=r4[1], a5=r5[0],b5=r5[1], a6=r6[0],b6=r6[1], a7=r7[0],b7=r7[1];
    acc16s(a,a0,b0,1.f); acc16s(a,a1,b1,1.f); acc16s(a,a2,b2,1.f); acc16s(a,a3,b3,1.f);
    acc16s(a,a4,b4,1.f); acc16s(a,a5,b5,1.f); acc16s(a,a6,b6,1.f); acc16s(a,a7,b7,1.f);
  }
  for(; e<e1; ++e){
    const uint4* r=(const uint4*)&h2[(size_t)srcs[e]*1024 + l*16];
    acc16s(a, r[0], r[1], 1.f);
  }
  uint4 o0, o1;
  o0.x=pk2(a[0],a[1]);   o0.y=pk2(a[2],a[3]);   o0.z=pk2(a[4],a[5]);   o0.w=pk2(a[6],a[7]);
  o1.x=pk2(a[8],a[9]);   o1.y=pk2(a[10],a[11]); o1.z=pk2(a[12],a[13]); o1.w=pk2(a[14],a[15]);
  uint4* zp = (uint4*)&z2[(size_t)node*1024 + l*16];
  zp[0]=o0; zp[1]=o1;
}

// ---------------------------------------------------------------------------
// K4b: GIN-1 MLP via MFMA (R5).
// ---------------------------------------------------------------------------
__global__ __launch_bounds__(256) void k_mm1(
  const u16* __restrict__ z1, const float* __restrict__ W1a, const float* __restrict__ b1a,
  const float* __restrict__ W1b, const float* __restrict__ b1b, u16* __restrict__ h2)
{
  __shared__ float tS[4][16*68 + 4];        // 17.5 KB, per-wave slices
  const int t=threadIdx.x, l=t&63, w=t>>6;
  const int col=l&15, quad=l>>4;

  bf16x8 fa[4], fb[4][2];
  float bav[4], bbv[4];
  #pragma unroll
  for(int nt=0;nt<4;++nt){
    fa[nt]    = bfragW(W1a, HM, 0,  nt*16, col, quad);   // k>=16 zeroed
    fb[nt][0] = bfragW(W1b, DP, 0,  nt*16, col, quad);
    fb[nt][1] = bfragW(W1b, DP, 32, nt*16, col, quad);
    bav[nt] = b1a[nt*16+col];
    bbv[nt] = b1b[nt*16+col];
  }
  for(int ni=0;ni<2;++ni){
    const int node = blockIdx.x*8 + ni*4 + w;
    bf16x8 a0;
    #pragma unroll
    for(int j=0;j<8;++j) a0[j]=0;
    if (quad < 2) a0 = *(const bf16x8*)&z1[(size_t)node*256 + col*16 + quad*8];
    #pragma unroll
    for(int nt=0;nt<4;++nt){
      f32x4 c = {bav[nt], bav[nt], bav[nt], bav[nt]};
      c = MFMA16(a0, fa[nt], c);
      #pragma unroll
      for(int r=0;r<4;++r)
        tS[w][(quad*4+r)*68 + nt*16 + col] = fmaxf(c[r], 0.f);
    }
    bf16x8 ta0 = afragT(&tS[w][col*68 + quad*8]);
    bf16x8 ta1 = afragT(&tS[w][col*68 + 32 + quad*8]);
    #pragma unroll
    for(int nt=0;nt<4;++nt){
      f32x4 c = {bbv[nt], bbv[nt], bbv[nt], bbv[nt]};
      c = MFMA16(ta0, fb[nt][0], c);
      c = MFMA16(ta1, fb[nt][1], c);
      #pragma unroll
      for(int r=0;r<4;++r)
        h2[(size_t)node*1024 + (quad*4+r)*64 + nt*16 + col] = f2b(fmaxf(c[r], 0.f));
    }
  }
}

// ---------------------------------------------------------------------------
// K5b: GIN-2 MLP via MFMA + ReLU + sum over M -> out f32 [NSUM,64]. (R5)
// ---------------------------------------------------------------------------
__global__ __launch_bounds__(256) void k_mm2(
  const u16* __restrict__ z2, const float* __restrict__ W2a, const float* __restrict__ b2a,
  const float* __restrict__ W2b, const float* __restrict__ b2b, float* __restrict__ out)
{
  __shared__ float tS[4][16*68 + 4];
  const int t=threadIdx.x, l=t&63, w=t>>6;
  const int col=l&15, quad=l>>4;

  bf16x8 fa[4][2], fb[4][2];
  float bav[4], bbv[4];
  #pragma unroll
  for(int nt=0;nt<4;++nt){
    fa[nt][0] = bfragW(W2a, DP, 0,  nt*16, col, quad);
    fa[nt][1] = bfragW(W2a, DP, 32, nt*16, col, quad);
    fb[nt][0] = bfragW(W2b, DP, 0,  nt*16, col, quad);
    fb[nt][1] = bfragW(W2b, DP, 32, nt*16, col, quad);
    bav[nt] = b2a[nt*16+col];
    bbv[nt] = b2b[nt*16+col];
  }
  for(int ni=0;ni<2;++ni){
    const int node = blockIdx.x*8 + ni*4 + w;
    const u16* zrow = &z2[(size_t)node*1024];
    bf16x8 a0 = *(const bf16x8*)&zrow[col*64 + quad*8];
    bf16x8 a1 = *(const bf16x8*)&zrow[col*64 + quad*8 + 32];
    #pragma unroll
    for(int nt=0;nt<4;++nt){
      f32x4 c = {bav[nt], bav[nt], bav[nt], bav[nt]};
      c = MFMA16(a0, fa[nt][0], c);
      c = MFMA16(a1, fa[nt][1], c);
      #pragma unroll
      for(int r=0;r<4;++r)
        tS[w][(quad*4+r)*68 + nt*16 + col] = fmaxf(c[r], 0.f);
    }
    bf16x8 ta0 = afragT(&tS[w][col*68 + quad*8]);
    bf16x8 ta1 = afragT(&tS[w][col*68 + 32 + quad*8]);
    #pragma unroll
    for(int nt=0;nt<4;++nt){
      f32x4 c = {bbv[nt], bbv[nt], bbv[nt], bbv[nt]};
      c = MFMA16(ta0, fb[nt][0], c);
      c = MFMA16(ta1, fb[nt][1], c);
      float s = fmaxf(c[0],0.f)+fmaxf(c[1],0.f)+fmaxf(c[2],0.f)+fmaxf(c[3],0.f);
      s += __shfl_xor(s, 16, 64);
      s += __shfl_xor(s, 32, 64);
      if (quad == 0)
        out[(size_t)node*64 + nt*16 + col] = s;
    }
  }
}

extern "C" void kernel_launch(void* const* d_in, const int* in_sizes, int n_in,
                              void* d_out, int out_size, void* d_ws, size_t ws_size,
                              hipStream_t stream)
{
  (void)in_sizes; (void)n_in; (void)out_size; (void)ws_size;
  const float* lap  = (const float*)d_in[0];
  const float* W0   = (const float*)d_in[1];
  const float* mlpW = (const float*)d_in[2];
  // d_in[3] = mlp_b: cancels inside BatchNorm (pure mean shift)
  const float* bng  = (const float*)d_in[4];
  const float* bnb  = (const float*)d_in[5];
  const float* eps1 = (const float*)d_in[6];
  const float* W1a  = (const float*)d_in[7];
  const float* b1a  = (const float*)d_in[8];
  const float* W1b  = (const float*)d_in[9];
  const float* b1b  = (const float*)d_in[10];
  const float* eps2 = (const float*)d_in[11];
  const float* W2a  = (const float*)d_in[12];
  const float* b2a  = (const float*)d_in[13];
  const float* W2b  = (const float*)d_in[14];
  const float* b2b  = (const float*)d_in[15];
  const int*   ei   = (const int*)d_in[16];
  const int* srcI = ei;
  const int* dstI = ei + NE;

  char* ws = (char*)d_ws;
  u16* h1   = (u16*)(ws);                    //  8,388,608 B  [16384][16][16]
  u16* z1   = (u16*)(ws + 8388608);          //  8,388,608 B
  u16* h2   = (u16*)(ws + 16777216);         // 33,554,432 B  [16384][16][64]
  u16* z2   = (u16*)(ws + 50331648);         // 33,554,432 B
  int* cnt  = (int*)(ws + 83886080);         //     65,536 B
  int* offA = (int*)(ws + 83951616);         //     65,792 B
  int* wpos = (int*)(ws + 84017408);         //     65,536 B
  int* srcs = (int*)(ws + 84082944);         //  1,048,576 B  (end 85,131,520)

  k_poly   <<<BG,      256, 0, stream>>>(lap, W0, mlpW, bng, bnb, h1, cnt);
  k_hist   <<<NE/256,  256, 0, stream>>>(dstI, cnt);
  k_scan   <<<1,       256, 0, stream>>>(cnt, offA, wpos);
  k_scatter<<<NE/256,  256, 0, stream>>>(srcI, dstI, wpos, srcs);
  k_agg1   <<<NSUM/4,  256, 0, stream>>>(h1, eps1, offA, srcs, z1);
  k_mm1    <<<NSUM/8,  256, 0, stream>>>(z1, W1a, b1a, W1b, b1b, h2);
  k_agg2   <<<NSUM/4,  256, 0, stream>>>(h2, eps2, offA, srcs, z2);
  k_mm2    <<<NSUM/8,  256, 0, stream>>>(z2, W2a, b2a, W2b, b2b, (float*)d_out);
}

// Round 11
// 257.387 us; speedup vs baseline: 1.7905x; 1.0958x over previous
//
#include <hip/hip_runtime.h>

typedef unsigned short u16;
typedef unsigned int   u32;
typedef short bf16x8 __attribute__((ext_vector_type(8)));
typedef float f32x4  __attribute__((ext_vector_type(4)));
typedef float f32x2  __attribute__((ext_vector_type(2)));

#define BG    128      // graphs
#define NN    128      // nodes per graph
#define MS    16       // samples
#define KP    8        // pearl_k
#define HM    16       // mlp hidden
#define DP    64       // pe dims
#define NSUM  16384    // BG*NN
#define NE    262144   // edges
#define SITES 2048     // NN*MS

// R3: inputs f32, output f32. Intermediates bf16.
// R10: poly = MFMA split-precision (best total 282us).
// R11: agg2 m-sliced with PERSISTENT chunk ownership: no shuffle epilogue
//   (R7's killer), fat dwordx4 loads (R6's killer), no LDS / low VGPR / 8192
//   blocks (R8's killer). h2 stored transposed h2T[m][node][d]; mm1 writes it
//   (R6-proven). agg1/mm2/CSR unchanged from R10.

__device__ __forceinline__ float blo(u32 u){ union{u32 i; float f;} v; v.i=u<<16; return v.f; }
__device__ __forceinline__ float bhi(u32 u){ union{u32 i; float f;} v; v.i=u&0xffff0000u; return v.f; }
__device__ __forceinline__ u16  f2b(float f){ union{float f; u32 i;} v; v.f=f; u32 x=v.i; x += 0x7fffu + ((x>>16)&1u); return (u16)(x>>16); }
__device__ __forceinline__ u32  pk2(float a, float b){ return (u32)f2b(a) | ((u32)f2b(b)<<16); }
__device__ __forceinline__ f32x2 up2(u32 u){ f32x2 v; v.x=blo(u); v.y=bhi(u); return v; }

__device__ __forceinline__ void fsplit(float x, short& hi, short& lo){
  u16 h = f2b(x); hi = (short)h; lo = (short)f2b(x - blo((u32)h));
}

__device__ __forceinline__ void acc4s(float* a, uint2 x, float s){
  a[0]+=s*blo(x.x); a[1]+=s*bhi(x.x); a[2]+=s*blo(x.y); a[3]+=s*bhi(x.y);
}

#define MFMA16(a,b,c) __builtin_amdgcn_mfma_f32_16x16x32_bf16(a,b,c,0,0,0)

__device__ __forceinline__ bf16x8 bfragW(const float* __restrict__ W, int nrows,
                                         int k0, int nb, int col, int quad){
  bf16x8 f;
  #pragma unroll
  for(int j=0;j<8;++j){
    int k = k0 + quad*8 + j;
    float v = (k < nrows) ? W[k*DP + nb + col] : 0.f;
    f[j] = (short)f2b(v);
  }
  return f;
}
__device__ __forceinline__ bf16x8 afragT(const float* tp){
  float4 v0 = *(const float4*)tp;
  float4 v1 = *(const float4*)(tp+4);
  bf16x8 a;
  a[0]=(short)f2b(v0.x); a[1]=(short)f2b(v0.y); a[2]=(short)f2b(v0.z); a[3]=(short)f2b(v0.w);
  a[4]=(short)f2b(v1.x); a[5]=(short)f2b(v1.y); a[6]=(short)f2b(v1.z); a[7]=(short)f2b(v1.w);
  return a;
}

// ---------------------------------------------------------------------------
// K1: poly filter via MFMA split-precision (R10, unchanged).
// ---------------------------------------------------------------------------
__global__ __launch_bounds__(256,1) void k_poly(
    const float* __restrict__ lap, const float* __restrict__ W0, const float* __restrict__ mlpW,
    const float* __restrict__ bng, const float* __restrict__ bnb, u16* __restrict__ h1,
    int* __restrict__ cnt)
{
  __shared__ float Wbuf[2][SITES];
  __shared__ float mlpWS[KP*HM];
  __shared__ float red[4][32];
  __shared__ float stat[32];
  __shared__ float ssc[HM], ssh[HM];

  const int b = blockIdx.x, t = threadIdx.x, l = t&63, w = t>>6;
  const int col = l&15, quad = l>>4;
  if (t < 128) cnt[b*128 + t] = 0;

  {
    const float4* src = (const float4*)(W0 + (size_t)b*SITES);
    for (int i=t; i<SITES/4; i+=256) ((float4*)Wbuf[0])[i] = src[i];
    if (t < KP*HM) mlpWS[t] = mlpW[t];
  }

  bf16x8 Ah[2][4], Al[2][4];
  {
    const float* lg = lap + (size_t)b*NN*NN;
    #pragma unroll
    for(int Mt=0;Mt<2;++Mt){
      const int nr = w*32 + Mt*16 + col;
      #pragma unroll
      for(int Kc=0;Kc<4;++Kc){
        const float* p = lg + (size_t)nr*NN + Kc*32 + quad*8;
        float4 v0 = *(const float4*)p;
        float4 v1 = *(const float4*)(p+4);
        float xs[8] = {v0.x,v0.y,v0.z,v0.w,v1.x,v1.y,v1.z,v1.w};
        #pragma unroll
        for(int j=0;j<8;++j){ short hi,lo; fsplit(xs[j],hi,lo); Ah[Mt][Kc][j]=hi; Al[Mt][Kc][j]=lo; }
      }
    }
  }

  float h[8][16];
  {
    const float* w0g = W0 + (size_t)b*SITES;
    #pragma unroll
    for(int Mt=0;Mt<2;++Mt){
      #pragma unroll
      for(int r=0;r<4;++r){
        const int n = w*32 + Mt*16 + quad*4 + r;
        float sv = w0g[n*MS + col];
        #pragma unroll
        for(int c=0;c<16;++c) h[Mt*4+r][c] = sv*mlpW[c];
      }
    }
  }
  __syncthreads();

  int cur=0;
  for(int k=1;k<KP;++k){
    f32x4 c0 = {0.f,0.f,0.f,0.f};
    f32x4 c1 = {0.f,0.f,0.f,0.f};
    #pragma unroll
    for(int Kc=0;Kc<4;++Kc){
      const float* wb = &Wbuf[cur][(Kc*32 + quad*8)*MS + col];
      bf16x8 Bh, Bl;
      #pragma unroll
      for(int j=0;j<8;++j){
        float x = wb[j*MS];
        short hi,lo; fsplit(x,hi,lo); Bh[j]=hi; Bl[j]=lo;
      }
      c0 = MFMA16(Ah[0][Kc], Bh, c0);
      c0 = MFMA16(Ah[0][Kc], Bl, c0);
      c0 = MFMA16(Al[0][Kc], Bh, c0);
      c1 = MFMA16(Ah[1][Kc], Bh, c1);
      c1 = MFMA16(Ah[1][Kc], Bl, c1);
      c1 = MFMA16(Al[1][Kc], Bh, c1);
    }
    float mw[16];
    #pragma unroll
    for(int c=0;c<16;++c) mw[c]=mlpWS[k*16+c];
    #pragma unroll
    for(int r=0;r<4;++r){
      const int n0 = w*32 + quad*4 + r;
      Wbuf[cur^1][n0*MS + col]        = c0[r];
      Wbuf[cur^1][(n0+16)*MS + col]   = c1[r];
      #pragma unroll
      for(int c=0;c<16;++c){ h[r][c] += c0[r]*mw[c]; h[4+r][c] += c1[r]*mw[c]; }
    }
    __syncthreads();
    cur ^= 1;
  }

  float sum[16], sq[16];
  #pragma unroll
  for(int c=0;c<16;++c){ sum[c]=0.f; sq[c]=0.f; }
  #pragma unroll
  for(int s=0;s<8;++s){
    #pragma unroll
    for(int c=0;c<16;++c){ float v=h[s][c]; sum[c]+=v; sq[c]+=v*v; }
  }
  #pragma unroll
  for(int d=1;d<64;d<<=1){
    #pragma unroll
    for(int c=0;c<16;++c){ sum[c]+=__shfl_xor(sum[c],d,64); sq[c]+=__shfl_xor(sq[c],d,64); }
  }
  if(l==0){
    #pragma unroll
    for(int c=0;c<16;++c){ red[w][c]=sum[c]; red[w][16+c]=sq[c]; }
  }
  __syncthreads();
  if(t<32) stat[t]=red[0][t]+red[1][t]+red[2][t]+red[3][t];
  __syncthreads();
  if(t<16){
    float mu  = stat[t]*(1.f/SITES);
    float var = stat[16+t]*(1.f/SITES) - mu*mu;
    float sc  = bng[t] * rsqrtf(var + 1e-5f);
    ssc[t]=sc; ssh[t]=bnb[t] - mu*sc;
  }
  __syncthreads();
  {
    float sc[16], sh[16];
    #pragma unroll
    for(int c=0;c<16;++c){ sc[c]=ssc[c]; sh[c]=ssh[c]; }
    #pragma unroll
    for(int s=0;s<8;++s){
      const int n = w*32 + (s>>2)*16 + quad*4 + (s&3);
      const int node = b*NN + n;
      float r[16];
      #pragma unroll
      for(int c=0;c<16;++c) r[c]=fmaxf(h[s][c]*sc[c]+sh[c], 0.f);
      uint4 A;
      A.x=pk2(r[0],r[1]);  A.y=pk2(r[2],r[3]);  A.z=pk2(r[4],r[5]);  A.w=pk2(r[6],r[7]);
      uint4 Bv;
      Bv.x=pk2(r[8],r[9]); Bv.y=pk2(r[10],r[11]); Bv.z=pk2(r[12],r[13]); Bv.w=pk2(r[14],r[15]);
      u16* o = h1 + (size_t)node*256 + (size_t)col*HM;
      *(uint4*)o     = A;
      *(uint4*)(o+8) = Bv;
    }
  }
}

// --------------------------- CSR build (by dst) ----------------------------
__global__ void k_hist(const int* __restrict__ dst, int* __restrict__ cnt){
  int e = blockIdx.x*256 + threadIdx.x;
  atomicAdd(&cnt[dst[e]], 1);
}

__global__ void k_scan(const int* __restrict__ cnt, int* __restrict__ off, int* __restrict__ wpos){
  __shared__ int ps[256];
  const int t = threadIdx.x, PER = NSUM/256;
  int s=0;
  for(int i=0;i<PER;++i) s += cnt[t*PER+i];
  ps[t]=s; __syncthreads();
  for(int d=1; d<256; d<<=1){
    int v = (t>=d) ? ps[t-d] : 0;
    __syncthreads();
    ps[t] += v;
    __syncthreads();
  }
  int run = (t==0) ? 0 : ps[t-1];
  for(int i=0;i<PER;++i){
    int idx=t*PER+i;
    off[idx]=run; wpos[idx]=run;
    run += cnt[idx];
  }
  if(t==255) off[NSUM]=run;
}

__global__ void k_scatter(const int* __restrict__ srcI, const int* __restrict__ dstI,
                          int* __restrict__ wpos, int* __restrict__ srcs){
  int e = blockIdx.x*256 + threadIdx.x;
  int p = atomicAdd(&wpos[dstI[e]], 1);
  srcs[p] = srcI[e];
}

// ---------------------------------------------------------------------------
// K4a: GIN-1 aggregate (R5/R10). 1 node/wave, persistent lane ownership,
// batch-8. h1/z1 row-major.
// ---------------------------------------------------------------------------
__global__ __launch_bounds__(256) void k_agg1(
  const u16* __restrict__ h1, const float* __restrict__ eps1p,
  const int* __restrict__ off, const int* __restrict__ srcs, u16* __restrict__ z1)
{
  const int t=threadIdx.x, l=t&63;
  const int node = blockIdx.x*4 + (t>>6);
  const float epe = 1.f + eps1p[0];
  float a[4] = {0.f,0.f,0.f,0.f};
  acc4s(a, *(const uint2*)&h1[(size_t)node*256 + l*4], epe);
  int e=off[node]; const int e1=off[node+1];
  for(; e+8<=e1; e+=8){
    int s0=srcs[e],s1=srcs[e+1],s2=srcs[e+2],s3=srcs[e+3];
    int s4=srcs[e+4],s5=srcs[e+5],s6=srcs[e+6],s7=srcs[e+7];
    uint2 r0=*(const uint2*)&h1[(size_t)s0*256 + l*4];
    uint2 r1=*(const uint2*)&h1[(size_t)s1*256 + l*4];
    uint2 r2=*(const uint2*)&h1[(size_t)s2*256 + l*4];
    uint2 r3=*(const uint2*)&h1[(size_t)s3*256 + l*4];
    uint2 r4=*(const uint2*)&h1[(size_t)s4*256 + l*4];
    uint2 r5=*(const uint2*)&h1[(size_t)s5*256 + l*4];
    uint2 r6=*(const uint2*)&h1[(size_t)s6*256 + l*4];
    uint2 r7=*(const uint2*)&h1[(size_t)s7*256 + l*4];
    acc4s(a,r0,1.f); acc4s(a,r1,1.f); acc4s(a,r2,1.f); acc4s(a,r3,1.f);
    acc4s(a,r4,1.f); acc4s(a,r5,1.f); acc4s(a,r6,1.f); acc4s(a,r7,1.f);
  }
  for(; e<e1; ++e){
    uint2 r=*(const uint2*)&h1[(size_t)srcs[e]*256 + l*4];
    acc4s(a,r,1.f);
  }
  uint2 o; o.x=pk2(a[0],a[1]); o.y=pk2(a[2],a[3]);
  *(uint2*)&z1[(size_t)node*256 + l*4] = o;
}

// ---------------------------------------------------------------------------
// K5a: GIN-2 aggregate, m-sliced + persistent chunk ownership.
// Block: m = blockIdx&15 (slices m,m+8 pinned per XCD via %8 dispatch),
// 4 waves x 8 nodes. Lane: group g=l>>3 (node), chunk q=l&7 (16B of 128B
// slice). One dwordx4 wave-inst = 8 edges. Degree divergence: wave-max loop
// + scale-predication (masked lanes accumulate x0, loads hit hot L2 lines).
// NO shuffles, NO LDS. z2 row-major [node][m][d].
// ---------------------------------------------------------------------------
__global__ __launch_bounds__(256) void k_agg2(
  const u16* __restrict__ h2T, const float* __restrict__ eps2p,
  const int* __restrict__ off, const int* __restrict__ srcs, u16* __restrict__ z2)
{
  const int t=threadIdx.x, l=t&63, w=t>>6;
  const int m = blockIdx.x & 15, g = blockIdx.x >> 4;
  const int grp = l>>3, q = l&7;
  const int node = g*32 + w*8 + grp;
  const float epe = 1.f + eps2p[0];
  const u16* __restrict__ base = h2T + (size_t)m*NSUM*DP;

  f32x2 A[4];
  {
    uint4 x = *(const uint4*)&base[(size_t)node*DP + q*8];
    f32x2 s2; s2.x=epe; s2.y=epe;
    A[0]=s2*up2(x.x); A[1]=s2*up2(x.y); A[2]=s2*up2(x.z); A[3]=s2*up2(x.w);
  }
  const int e0 = off[node], e1 = off[node+1];
  int dmax = e1 - e0;
  #pragma unroll
  for(int d=1; d<64; d<<=1) dmax = max(dmax, __shfl_xor(dmax, d, 64));

  int i = 0;
  for(; i+2 <= dmax; i += 2){
    int pa = e0+i, pb = e0+i+1;
    float sa = (pa < e1) ? 1.f : 0.f;
    float sb = (pb < e1) ? 1.f : 0.f;
    int ea = min(pa, NE-1), eb = min(pb, NE-1);
    int ia = srcs[ea], ib = srcs[eb];
    uint4 xa = *(const uint4*)&base[(size_t)ia*DP + q*8];
    uint4 xb = *(const uint4*)&base[(size_t)ib*DP + q*8];
    f32x2 va; va.x=sa; va.y=sa;
    f32x2 vb; vb.x=sb; vb.y=sb;
    A[0]+=va*up2(xa.x); A[1]+=va*up2(xa.y); A[2]+=va*up2(xa.z); A[3]+=va*up2(xa.w);
    A[0]+=vb*up2(xb.x); A[1]+=vb*up2(xb.y); A[2]+=vb*up2(xb.z); A[3]+=vb*up2(xb.w);
  }
  if(i < dmax){
    int pa = e0+i;
    float sa = (pa < e1) ? 1.f : 0.f;
    int ea = min(pa, NE-1);
    int ia = srcs[ea];
    uint4 xa = *(const uint4*)&base[(size_t)ia*DP + q*8];
    f32x2 va; va.x=sa; va.y=sa;
    A[0]+=va*up2(xa.x); A[1]+=va*up2(xa.y); A[2]+=va*up2(xa.z); A[3]+=va*up2(xa.w);
  }

  uint4 o;
  o.x=pk2(A[0].x,A[0].y); o.y=pk2(A[1].x,A[1].y);
  o.z=pk2(A[2].x,A[2].y); o.w=pk2(A[3].x,A[3].y);
  *(uint4*)&z2[(size_t)node*1024 + m*DP + q*8] = o;
}

// ---------------------------------------------------------------------------
// K4b: GIN-1 MLP via MFMA; writes h2 TRANSPOSED h2T[m][node][d] (R6-proven).
// ---------------------------------------------------------------------------
__global__ __launch_bounds__(256) void k_mm1(
  const u16* __restrict__ z1, const float* __restrict__ W1a, const float* __restrict__ b1a,
  const float* __restrict__ W1b, const float* __restrict__ b1b, u16* __restrict__ h2T)
{
  __shared__ float tS[4][16*68 + 4];
  const int t=threadIdx.x, l=t&63, w=t>>6;
  const int col=l&15, quad=l>>4;

  bf16x8 fa[4], fb[4][2];
  float bav[4], bbv[4];
  #pragma unroll
  for(int nt=0;nt<4;++nt){
    fa[nt]    = bfragW(W1a, HM, 0,  nt*16, col, quad);   // k>=16 zeroed
    fb[nt][0] = bfragW(W1b, DP, 0,  nt*16, col, quad);
    fb[nt][1] = bfragW(W1b, DP, 32, nt*16, col, quad);
    bav[nt] = b1a[nt*16+col];
    bbv[nt] = b1b[nt*16+col];
  }
  for(int ni=0;ni<2;++ni){
    const int node = blockIdx.x*8 + ni*4 + w;
    bf16x8 a0;
    #pragma unroll
    for(int j=0;j<8;++j) a0[j]=0;
    if (quad < 2) a0 = *(const bf16x8*)&z1[(size_t)node*256 + col*16 + quad*8];
    #pragma unroll
    for(int nt=0;nt<4;++nt){
      f32x4 c = {bav[nt], bav[nt], bav[nt], bav[nt]};
      c = MFMA16(a0, fa[nt], c);
      #pragma unroll
      for(int r=0;r<4;++r)
        tS[w][(quad*4+r)*68 + nt*16 + col] = fmaxf(c[r], 0.f);
    }
    bf16x8 ta0 = afragT(&tS[w][col*68 + quad*8]);
    bf16x8 ta1 = afragT(&tS[w][col*68 + 32 + quad*8]);
    #pragma unroll
    for(int nt=0;nt<4;++nt){
      f32x4 c = {bbv[nt], bbv[nt], bbv[nt], bbv[nt]};
      c = MFMA16(ta0, fb[nt][0], c);
      c = MFMA16(ta1, fb[nt][1], c);
      #pragma unroll
      for(int r=0;r<4;++r)
        h2T[((size_t)(quad*4+r)*NSUM + node)*DP + nt*16 + col] = f2b(fmaxf(c[r], 0.f));
    }
  }
}

// ---------------------------------------------------------------------------
// K5b: GIN-2 MLP via MFMA + ReLU + sum over M -> out f32 [NSUM,64]. (R5)
// ---------------------------------------------------------------------------
__global__ __launch_bounds__(256) void k_mm2(
  const u16* __restrict__ z2, const float* __restrict__ W2a, const float* __restrict__ b2a,
  const float* __restrict__ W2b, const float* __restrict__ b2b, float* __restrict__ out)
{
  __shared__ float tS[4][16*68 + 4];
  const int t=threadIdx.x, l=t&63, w=t>>6;
  const int col=l&15, quad=l>>4;

  bf16x8 fa[4][2], fb[4][2];
  float bav[4], bbv[4];
  #pragma unroll
  for(int nt=0;nt<4;++nt){
    fa[nt][0] = bfragW(W2a, DP, 0,  nt*16, col, quad);
    fa[nt][1] = bfragW(W2a, DP, 32, nt*16, col, quad);
    fb[nt][0] = bfragW(W2b, DP, 0,  nt*16, col, quad);
    fb[nt][1] = bfragW(W2b, DP, 32, nt*16, col, quad);
    bav[nt] = b2a[nt*16+col];
    bbv[nt] = b2b[nt*16+col];
  }
  for(int ni=0;ni<2;++ni){
    const int node = blockIdx.x*8 + ni*4 + w;
    const u16* zrow = &z2[(size_t)node*1024];
    bf16x8 a0 = *(const bf16x8*)&zrow[col*64 + quad*8];
    bf16x8 a1 = *(const bf16x8*)&zrow[col*64 + quad*8 + 32];
    #pragma unroll
    for(int nt=0;nt<4;++nt){
      f32x4 c = {bav[nt], bav[nt], bav[nt], bav[nt]};
      c = MFMA16(a0, fa[nt][0], c);
      c = MFMA16(a1, fa[nt][1], c);
      #pragma unroll
      for(int r=0;r<4;++r)
        tS[w][(quad*4+r)*68 + nt*16 + col] = fmaxf(c[r], 0.f);
    }
    bf16x8 ta0 = afragT(&tS[w][col*68 + quad*8]);
    bf16x8 ta1 = afragT(&tS[w][col*68 + 32 + quad*8]);
    #pragma unroll
    for(int nt=0;nt<4;++nt){
      f32x4 c = {bbv[nt], bbv[nt], bbv[nt], bbv[nt]};
      c = MFMA16(ta0, fb[nt][0], c);
      c = MFMA16(ta1, fb[nt][1], c);
      float s = fmaxf(c[0],0.f)+fmaxf(c[1],0.f)+fmaxf(c[2],0.f)+fmaxf(c[3],0.f);
      s += __shfl_xor(s, 16, 64);
      s += __shfl_xor(s, 32, 64);
      if (quad == 0)
        out[(size_t)node*64 + nt*16 + col] = s;
    }
  }
}

extern "C" void kernel_launch(void* const* d_in, const int* in_sizes, int n_in,
                              void* d_out, int out_size, void* d_ws, size_t ws_size,
                              hipStream_t stream)
{
  (void)in_sizes; (void)n_in; (void)out_size; (void)ws_size;
  const float* lap  = (const float*)d_in[0];
  const float* W0   = (const float*)d_in[1];
  const float* mlpW = (const float*)d_in[2];
  // d_in[3] = mlp_b: cancels inside BatchNorm (pure mean shift)
  const float* bng  = (const float*)d_in[4];
  const float* bnb  = (const float*)d_in[5];
  const float* eps1 = (const float*)d_in[6];
  const float* W1a  = (const float*)d_in[7];
  const float* b1a  = (const float*)d_in[8];
  const float* W1b  = (const float*)d_in[9];
  const float* b1b  = (const float*)d_in[10];
  const float* eps2 = (const float*)d_in[11];
  const float* W2a  = (const float*)d_in[12];
  const float* b2a  = (const float*)d_in[13];
  const float* W2b  = (const float*)d_in[14];
  const float* b2b  = (const float*)d_in[15];
  const int*   ei   = (const int*)d_in[16];
  const int* srcI = ei;
  const int* dstI = ei + NE;

  char* ws = (char*)d_ws;
  u16* h1   = (u16*)(ws);                    //  8,388,608 B  [16384][16][16]
  u16* z1   = (u16*)(ws + 8388608);          //  8,388,608 B
  u16* h2T  = (u16*)(ws + 16777216);         // 33,554,432 B  [16][16384][64]
  u16* z2   = (u16*)(ws + 50331648);         // 33,554,432 B  [16384][16][64]
  int* cnt  = (int*)(ws + 83886080);         //     65,536 B
  int* offA = (int*)(ws + 83951616);         //     65,792 B
  int* wpos = (int*)(ws + 84017408);         //     65,536 B
  int* srcs = (int*)(ws + 84082944);         //  1,048,576 B  (end 85,131,520)

  k_poly   <<<BG,      256, 0, stream>>>(lap, W0, mlpW, bng, bnb, h1, cnt);
  k_hist   <<<NE/256,  256, 0, stream>>>(dstI, cnt);
  k_scan   <<<1,       256, 0, stream>>>(cnt, offA, wpos);
  k_scatter<<<NE/256,  256, 0, stream>>>(srcI, dstI, wpos, srcs);
  k_agg1   <<<NSUM/4,  256, 0, stream>>>(h1, eps1, offA, srcs, z1);
  k_mm1    <<<NSUM/8,  256, 0, stream>>>(z1, W1a, b1a, W1b, b1b, h2T);
  k_agg2   <<<16*(NSUM/32), 256, 0, stream>>>(h2T, eps2, offA, srcs, z2);
  k_mm2    <<<NSUM/8,  256, 0, stream>>>(z2, W2a, b2a, W2b, b2b, (float*)d_out);
}